// Round 2
// baseline (1804.028 us; speedup 1.0000x reference)
//
#include <hip/hip_runtime.h>
#include <hip/hip_bf16.h>

typedef unsigned short u16;
typedef unsigned int   u32;

#define B_N   256
#define S_N   512
#define BSN   (B_N * S_N)      // 131072 positions
#define MEMN  32
#define DKN   128
#define DVN   128
#define DSN   256

// ---------- helpers ----------
__device__ __forceinline__ float bf2f(u16 u) {
  union { u32 i; float f; } v; v.i = ((u32)u) << 16; return v.f;
}
__device__ __forceinline__ u16 f2bf(float f) {
  union { float f; u32 i; } v; v.f = f;
  u32 x = v.i;
  x += 0x7fffu + ((x >> 16) & 1u);   // RNE
  return (u16)(x >> 16);
}
__device__ __forceinline__ u32 pack2(float a, float b) {
  return (u32)f2bf(a) | ((u32)f2bf(b) << 16);
}
__device__ __forceinline__ float sigmoid_fast(float x) { return 1.f / (1.f + __expf(-x)); }
__device__ __forceinline__ float tanh_fast(float x)    { return 1.f - 2.f / (__expf(2.f * x) + 1.f); }

// ============================================================
// kErAdd: erase = sigmoid(qae@W_erase+b), add = tanh(qae@W_add+b)
// inputs f32, outputs bf16. grid (BSN/32, 2), block 256. y: 0=erase, 1=add
// ============================================================
__global__ __launch_bounds__(256) void kErAdd(
    const int* __restrict__ qa_data, const float* __restrict__ qa_table,
    const float* __restrict__ W0, const float* __restrict__ b0,
    const float* __restrict__ W1, const float* __restrict__ b1,
    u16* __restrict__ out0, u16* __restrict__ out1)
{
  __shared__ __align__(16) float Wl[DVN * DVN];   // 64 KB
  __shared__ __align__(16) float Xt[DVN * 32];    // 16 KB, [k][r]
  __shared__ int idx[32];
  const int tid = threadIdx.x;
  const int p0  = blockIdx.x * 32;
  const int sel = blockIdx.y;
  const float* W    = sel ? W1 : W0;
  const float* bb   = sel ? b1 : b0;
  u16*         outp = sel ? out1 : out0;

  if (tid < 32) idx[tid] = qa_data[p0 + tid];
  { // stage W (128x128 f32 = 4096 float4)
    const float4* Wg = (const float4*)W;
    float4* Ws = (float4*)Wl;
    #pragma unroll
    for (int u = 0; u < 16; ++u) Ws[tid + 256 * u] = Wg[tid + 256 * u];
  }
  __syncthreads();   // idx visible
  { // stage Xt transposed
    const int r = tid & 31, cb = tid >> 5;
    #pragma unroll
    for (int u = 0; u < 4; ++u) {
      const int k0 = cb * 16 + u * 4;
      const float4 raw = *(const float4*)(qa_table + (long)idx[r] * DVN + k0);
      Xt[(k0 + 0) * 32 + r] = raw.x;
      Xt[(k0 + 1) * 32 + r] = raw.y;
      Xt[(k0 + 2) * 32 + r] = raw.z;
      Xt[(k0 + 3) * 32 + r] = raw.w;
    }
  }
  __syncthreads();

  const int jp = tid & 63;   // outputs j = 2*jp, 2*jp+1
  const int rg = tid >> 6;   // rows rg*8 .. rg*8+7
  float acc0[8], acc1[8];
  const float bv0 = bb[2 * jp], bv1 = bb[2 * jp + 1];
  #pragma unroll
  for (int i = 0; i < 8; ++i) { acc0[i] = bv0; acc1[i] = bv1; }

  #pragma unroll 4
  for (int k = 0; k < DVN; ++k) {
    const float2 wp = *(const float2*)(Wl + k * DVN + 2 * jp);
    const float4 xa = *(const float4*)(Xt + k * 32 + rg * 8);
    const float4 xb = *(const float4*)(Xt + k * 32 + rg * 8 + 4);
    const float xs[8] = {xa.x, xa.y, xa.z, xa.w, xb.x, xb.y, xb.z, xb.w};
    #pragma unroll
    for (int i = 0; i < 8; ++i) {
      acc0[i] = fmaf(xs[i], wp.x, acc0[i]);
      acc1[i] = fmaf(xs[i], wp.y, acc1[i]);
    }
  }
  #pragma unroll
  for (int i = 0; i < 8; ++i) {
    const int p = p0 + rg * 8 + i;
    float a0 = acc0[i], a1 = acc1[i];
    if (sel == 0) { a0 = sigmoid_fast(a0); a1 = sigmoid_fast(a1); }
    else          { a0 = tanh_fast(a0);    a1 = tanh_fast(a1);    }
    *(u32*)(outp + (long)p * DVN + 2 * jp) = pack2(a0, a1);
  }
}

// ============================================================
// kQe: attention weights w (softmax), difficulty head, qe->summary-in copy
// grid (BSN/32), block 256
// ============================================================
__global__ __launch_bounds__(256) void kQe(
    const int* __restrict__ q_data, const float* __restrict__ q_table,
    const float* __restrict__ key_mem,
    const float* __restrict__ Wdf1, const float* __restrict__ bdf1,
    const float* __restrict__ Wdf2, const float* __restrict__ bdf2,
    float* __restrict__ w_all, float* __restrict__ diff,
    u16* __restrict__ sin_buf)
{
  __shared__ __align__(16) float Wl[DKN * DKN];    // 64 KB
  __shared__ __align__(16) float Xt[DKN * 32];     // 16 KB, [k][r] (qe rows)
  __shared__ __align__(16) float Kt[DKN * 32];     // 16 KB, [k][m]; reused as H[32][128]
  __shared__ int idx[32];
  const int tid = threadIdx.x;
  const int p0  = blockIdx.x * 32;

  if (tid < 32) idx[tid] = q_data[p0 + tid];
  { // stage W_df1
    const float4* Wg = (const float4*)Wdf1;
    float4* Ws = (float4*)Wl;
    #pragma unroll
    for (int u = 0; u < 16; ++u) Ws[tid + 256 * u] = Wg[tid + 256 * u];
  }
  __syncthreads();
  { // stage Xt (qe, transposed)
    const int r = tid & 31, cb = tid >> 5;
    #pragma unroll
    for (int u = 0; u < 4; ++u) {
      const int k0 = cb * 16 + u * 4;
      const float4 raw = *(const float4*)(q_table + (long)idx[r] * DKN + k0);
      Xt[(k0 + 0) * 32 + r] = raw.x;
      Xt[(k0 + 1) * 32 + r] = raw.y;
      Xt[(k0 + 2) * 32 + r] = raw.z;
      Xt[(k0 + 3) * 32 + r] = raw.w;
    }
  }
  { // stage key_memory transposed: Kt[k*32+m]
    const int m = tid & 31, cb = tid >> 5;
    #pragma unroll
    for (int u = 0; u < 4; ++u) {
      const int k0 = cb * 16 + u * 4;
      const float4 raw = *(const float4*)(key_mem + m * DKN + k0);
      Kt[(k0 + 0) * 32 + m] = raw.x;
      Kt[(k0 + 1) * 32 + m] = raw.y;
      Kt[(k0 + 2) * 32 + m] = raw.z;
      Kt[(k0 + 3) * 32 + m] = raw.w;
    }
  }
  __syncthreads();

  // ---- attention scores + softmax (thread: pos=tid>>3, 4 m's each) ----
  {
    const int pos = tid >> 3;
    const int m4  = (tid & 7) * 4;
    float s0 = 0.f, s1 = 0.f, s2 = 0.f, s3 = 0.f;
    #pragma unroll 4
    for (int k = 0; k < DKN; ++k) {
      const float x = Xt[k * 32 + pos];
      const float4 kv = *(const float4*)(Kt + k * 32 + m4);
      s0 = fmaf(x, kv.x, s0);
      s1 = fmaf(x, kv.y, s1);
      s2 = fmaf(x, kv.z, s2);
      s3 = fmaf(x, kv.w, s3);
    }
    float mx = fmaxf(fmaxf(s0, s1), fmaxf(s2, s3));
    #pragma unroll
    for (int d = 1; d <= 4; d <<= 1) mx = fmaxf(mx, __shfl_xor(mx, d, 64));
    const float e0 = __expf(s0 - mx), e1 = __expf(s1 - mx);
    const float e2 = __expf(s2 - mx), e3 = __expf(s3 - mx);
    float sm = e0 + e1 + e2 + e3;
    #pragma unroll
    for (int d = 1; d <= 4; d <<= 1) sm += __shfl_xor(sm, d, 64);
    const float inv = 1.f / sm;
    const float4 wv = make_float4(e0 * inv, e1 * inv, e2 * inv, e3 * inv);
    *(float4*)(w_all + (long)(p0 + pos) * MEMN + m4) = wv;
  }
  __syncthreads();   // all Kt reads done before H overwrites it

  // ---- difficulty hidden = tanh(qe @ W_df1 + b) ----
  const int jp = tid & 63;
  const int rg = tid >> 6;
  {
    float acc0[8], acc1[8];
    const float bv0 = bdf1[2 * jp], bv1 = bdf1[2 * jp + 1];
    #pragma unroll
    for (int i = 0; i < 8; ++i) { acc0[i] = bv0; acc1[i] = bv1; }
    #pragma unroll 4
    for (int k = 0; k < DKN; ++k) {
      const float2 wp = *(const float2*)(Wl + k * DKN + 2 * jp);
      const float4 xa = *(const float4*)(Xt + k * 32 + rg * 8);
      const float4 xb = *(const float4*)(Xt + k * 32 + rg * 8 + 4);
      const float xs[8] = {xa.x, xa.y, xa.z, xa.w, xb.x, xb.y, xb.z, xb.w};
      #pragma unroll
      for (int i = 0; i < 8; ++i) {
        acc0[i] = fmaf(xs[i], wp.x, acc0[i]);
        acc1[i] = fmaf(xs[i], wp.y, acc1[i]);
      }
    }
    float* H = Kt;   // reuse (32 rows x 128 f32 = 16 KB)
    #pragma unroll
    for (int i = 0; i < 8; ++i) {
      const int r = rg * 8 + i;
      H[r * DKN + 2 * jp]     = tanh_fast(acc0[i]);
      H[r * DKN + 2 * jp + 1] = tanh_fast(acc1[i]);
    }
  }
  __syncthreads();

  // ---- difficulty = H . W_df2 + b_df2 (one wave per 8 rows) ----
  {
    const float* H = Kt;
    const int wv   = tid >> 6;
    const int lane = tid & 63;
    const float w2a = Wdf2[lane], w2b = Wdf2[64 + lane];
    const float bd  = bdf2[0];
    #pragma unroll
    for (int r8 = 0; r8 < 8; ++r8) {
      const int r = wv * 8 + r8;
      float sgm = H[r * DKN + lane] * w2a + H[r * DKN + 64 + lane] * w2b;
      #pragma unroll
      for (int d = 1; d < 64; d <<= 1) sgm += __shfl_xor(sgm, d, 64);
      if (lane == 0) diff[p0 + r] = sgm + bd;
    }
  }

  // ---- copy qe into summary-input right half (f32 -> bf16) ----
  {
    #pragma unroll
    for (int u = 0; u < 4; ++u) {
      const int c = tid + 256 * u;          // 0..1023 quads
      const int r = c >> 5, k0 = (c & 31) * 4;
      const float4 raw = *(const float4*)(q_table + (long)idx[r] * DKN + k0);
      uint2 two;
      two.x = pack2(raw.x, raw.y);
      two.y = pack2(raw.z, raw.w);
      *(uint2*)(sin_buf + (long)(p0 + r) * DSN + DKN + k0) = two;
    }
  }
}

// ============================================================
// kScan: sequential DKVMN value-memory recurrence. grid (B_N), block 512.
// Mv in registers (8 f32/thread). thread: col c = tid>>2, rows (tid&3)*8..+7
// ============================================================
__global__ __launch_bounds__(512) void kScan(
    const float* __restrict__ w_all, const u16* __restrict__ eras,
    const u16* __restrict__ addb, const float* __restrict__ init_mem,
    u16* __restrict__ sin_buf)
{
  const int tid = threadIdx.x;
  const int c = tid >> 2;
  const int q = tid & 3;
  float Mv[8];
  #pragma unroll
  for (int i = 0; i < 8; ++i) Mv[i] = init_mem[(q * 8 + i) * DVN + c];

  int p = blockIdx.x * S_N;
  float4 wA = *(const float4*)(w_all + (long)p * MEMN + q * 8);
  float4 wB = *(const float4*)(w_all + (long)p * MEMN + q * 8 + 4);
  float ec = bf2f(eras[(long)p * DVN + c]);
  float ac = bf2f(addb[(long)p * DVN + c]);

  for (int s = 0; s < S_N; ++s, ++p) {
    const int pn = (s == S_N - 1) ? p : p + 1;
    // prefetch next step
    const float4 wAn = *(const float4*)(w_all + (long)pn * MEMN + q * 8);
    const float4 wBn = *(const float4*)(w_all + (long)pn * MEMN + q * 8 + 4);
    const u16 en = eras[(long)pn * DVN + c];
    const u16 an = addb[(long)pn * DVN + c];

    const float wr[8] = {wA.x, wA.y, wA.z, wA.w, wB.x, wB.y, wB.z, wB.w};
    // read BEFORE write
    float pr = 0.f;
    #pragma unroll
    for (int i = 0; i < 8; ++i) pr = fmaf(wr[i], Mv[i], pr);
    pr += __shfl_xor(pr, 1, 64);
    pr += __shfl_xor(pr, 2, 64);
    if (q == 0) sin_buf[(long)p * DSN + c] = f2bf(pr);
    // Mv = Mv*(1 - w*e) + w*a
    #pragma unroll
    for (int i = 0; i < 8; ++i) {
      const float t1 = wr[i] * ec;
      const float u  = fmaf(wr[i], ac, Mv[i]);
      Mv[i] = fmaf(-Mv[i], t1, u);
    }
    wA = wAn; wB = wBn; ec = bf2f(en); ac = bf2f(an);
  }
}

// ============================================================
// kSum: summary = tanh(sin @ W_sum + b_sum)   [BS,256]x[256,256]
// X bf16, W/bias f32, Y bf16. grid (BSN/32, 4), block 256.
// ============================================================
__global__ __launch_bounds__(256) void kSum(
    const u16* __restrict__ X, const float* __restrict__ W,
    const float* __restrict__ bias, u16* __restrict__ Y)
{
  __shared__ __align__(16) float Wl[DSN * 64];   // 64 KB
  __shared__ __align__(16) float Xt[DSN * 32];   // 32 KB
  const int tid = threadIdx.x;
  const int p0  = blockIdx.x * 32;
  const int j0  = blockIdx.y * 64;
  { // stage W column tile (256 rows x 64 cols = 4096 float4)
    #pragma unroll
    for (int u = 0; u < 16; ++u) {
      const int cidx = tid + 256 * u;            // 0..4095
      const int k = cidx >> 4, c4 = (cidx & 15) * 4;
      const float4 raw = *(const float4*)(W + (long)k * DSN + j0 + c4);
      *(float4*)(Wl + k * 64 + c4) = raw;
    }
  }
  { // stage Xt transposed (bf16 source)
    const int r = tid & 31, cb = tid >> 5;
    #pragma unroll
    for (int u = 0; u < 4; ++u) {
      const int k0 = (cb * 4 + u) * 8;
      uint4 raw = *(const uint4*)(X + (long)(p0 + r) * DSN + k0);
      const u16* h = (const u16*)&raw;
      #pragma unroll
      for (int q = 0; q < 8; ++q) Xt[(k0 + q) * 32 + r] = bf2f(h[q]);
    }
  }
  __syncthreads();

  const int jp = tid & 31;   // outputs j0+2*jp, j0+2*jp+1
  const int rg = tid >> 5;   // rows rg*4 .. rg*4+3
  float acc0[4], acc1[4];
  const float bv0 = bias[j0 + 2 * jp], bv1 = bias[j0 + 2 * jp + 1];
  #pragma unroll
  for (int i = 0; i < 4; ++i) { acc0[i] = bv0; acc1[i] = bv1; }

  #pragma unroll 4
  for (int k = 0; k < DSN; ++k) {
    const float2 wp = *(const float2*)(Wl + k * 64 + 2 * jp);
    const float4 xa = *(const float4*)(Xt + k * 32 + rg * 4);
    acc0[0] = fmaf(xa.x, wp.x, acc0[0]); acc1[0] = fmaf(xa.x, wp.y, acc1[0]);
    acc0[1] = fmaf(xa.y, wp.x, acc0[1]); acc1[1] = fmaf(xa.y, wp.y, acc1[1]);
    acc0[2] = fmaf(xa.z, wp.x, acc0[2]); acc1[2] = fmaf(xa.z, wp.y, acc1[2]);
    acc0[3] = fmaf(xa.w, wp.x, acc0[3]); acc1[3] = fmaf(xa.w, wp.y, acc1[3]);
  }
  #pragma unroll
  for (int i = 0; i < 4; ++i) {
    const int p = p0 + rg * 4 + i;
    *(u32*)(Y + (long)p * DSN + j0 + 2 * jp) = pack2(tanh_fast(acc0[i]), tanh_fast(acc1[i]));
  }
}

// ============================================================
// kAb: partial[y][p] = sum_{j in tile} tanh(summary@W_ab1+b)[j] * W_ab2[j]
// grid (BSN/32, 4), block 256.
// ============================================================
__global__ __launch_bounds__(256) void kAb(
    const u16* __restrict__ X, const float* __restrict__ W,
    const float* __restrict__ bias, const float* __restrict__ Wab2,
    float* __restrict__ part)
{
  __shared__ __align__(16) float Wl[DSN * 64];
  __shared__ __align__(16) float Xt[DSN * 32];
  const int tid = threadIdx.x;
  const int p0  = blockIdx.x * 32;
  const int j0  = blockIdx.y * 64;
  {
    #pragma unroll
    for (int u = 0; u < 16; ++u) {
      const int cidx = tid + 256 * u;
      const int k = cidx >> 4, c4 = (cidx & 15) * 4;
      const float4 raw = *(const float4*)(W + (long)k * DSN + j0 + c4);
      *(float4*)(Wl + k * 64 + c4) = raw;
    }
  }
  {
    const int r = tid & 31, cb = tid >> 5;
    #pragma unroll
    for (int u = 0; u < 4; ++u) {
      const int k0 = (cb * 4 + u) * 8;
      uint4 raw = *(const uint4*)(X + (long)(p0 + r) * DSN + k0);
      const u16* h = (const u16*)&raw;
      #pragma unroll
      for (int q = 0; q < 8; ++q) Xt[(k0 + q) * 32 + r] = bf2f(h[q]);
    }
  }
  __syncthreads();

  const int jp = tid & 31;
  const int rg = tid >> 5;
  float acc0[4], acc1[4];
  const float bv0 = bias[j0 + 2 * jp], bv1 = bias[j0 + 2 * jp + 1];
  #pragma unroll
  for (int i = 0; i < 4; ++i) { acc0[i] = bv0; acc1[i] = bv1; }

  #pragma unroll 4
  for (int k = 0; k < DSN; ++k) {
    const float2 wp = *(const float2*)(Wl + k * 64 + 2 * jp);
    const float4 xa = *(const float4*)(Xt + k * 32 + rg * 4);
    acc0[0] = fmaf(xa.x, wp.x, acc0[0]); acc1[0] = fmaf(xa.x, wp.y, acc1[0]);
    acc0[1] = fmaf(xa.y, wp.x, acc0[1]); acc1[1] = fmaf(xa.y, wp.y, acc1[1]);
    acc0[2] = fmaf(xa.z, wp.x, acc0[2]); acc1[2] = fmaf(xa.z, wp.y, acc1[2]);
    acc0[3] = fmaf(xa.w, wp.x, acc0[3]); acc1[3] = fmaf(xa.w, wp.y, acc1[3]);
  }
  const float w2a = Wab2[j0 + 2 * jp];
  const float w2b = Wab2[j0 + 2 * jp + 1];
  #pragma unroll
  for (int i = 0; i < 4; ++i) {
    float s = tanh_fast(acc0[i]) * w2a + tanh_fast(acc1[i]) * w2b;
    #pragma unroll
    for (int d = 1; d < 32; d <<= 1) s += __shfl_xor(s, d, 64);
    if (jp == 0) part[(long)blockIdx.y * BSN + p0 + rg * 4 + i] = s;
  }
}

// ============================================================
// kOut: combine. grid (BSN/256), block 256. f32 output.
// ============================================================
__global__ __launch_bounds__(256) void kOut(
    const float* __restrict__ part, const float* __restrict__ diff,
    const float* __restrict__ bab2, float* __restrict__ out)
{
  const int p = blockIdx.x * 256 + threadIdx.x;
  const float ab = part[p] + part[BSN + p] + part[2 * BSN + p] + part[3 * BSN + p]
                   + bab2[0];
  const float d  = diff[p];
  const float z  = 3.0f * ab - d;
  out[p]           = sigmoid_fast(z);
  out[BSN + p]     = ab;
  out[2 * BSN + p] = d;
  out[3 * BSN + p] = z;
}

// ============================================================
// launch
// ============================================================
extern "C" void kernel_launch(void* const* d_in, const int* in_sizes, int n_in,
                              void* d_out, int out_size, void* d_ws, size_t ws_size,
                              hipStream_t stream)
{
  const int*   q_data   = (const int*)d_in[0];
  const int*   qa_data  = (const int*)d_in[1];
  const float* q_table  = (const float*)d_in[2];
  const float* qa_table = (const float*)d_in[3];
  const float* key_mem  = (const float*)d_in[4];
  const float* init_mem = (const float*)d_in[5];
  const float* W_erase  = (const float*)d_in[6];
  const float* b_erase  = (const float*)d_in[7];
  const float* W_add    = (const float*)d_in[8];
  const float* b_add    = (const float*)d_in[9];
  const float* W_sum    = (const float*)d_in[10];
  const float* b_sum    = (const float*)d_in[11];
  const float* W_ab1    = (const float*)d_in[12];
  const float* b_ab1    = (const float*)d_in[13];
  const float* W_ab2    = (const float*)d_in[14];
  const float* b_ab2    = (const float*)d_in[15];
  const float* W_df1    = (const float*)d_in[16];
  const float* b_df1    = (const float*)d_in[17];
  const float* W_df2    = (const float*)d_in[18];
  const float* b_df2    = (const float*)d_in[19];

  // workspace layout (bytes); total 153,616,384 (~146.5 MB)
  char* ws = (char*)d_ws;
  float* w_all = (float*)(ws + 0);           // [BS][32] f32   16,777,216
  u16*   eras  = (u16*)(ws + 16777216);      // [BS][128] bf16 33,554,432
  u16*   addb  = (u16*)(ws + 50331648);      // [BS][128] bf16 33,554,432
  u16*   sinb  = (u16*)(ws + 83886080);      // [BS][256] bf16 67,108,864 (reads|qe)
  float* diffb = (float*)(ws + 150994944);   // [BS] f32          524,288
  float* part  = (float*)(ws + 151519232);   // [4][BS] f32     2,097,152
  u16*   summ  = eras;                       // summary reuses eras+addb (dead after scan)

  kErAdd<<<dim3(BSN / 32, 2), 256, 0, stream>>>(qa_data, qa_table, W_erase, b_erase,
                                                W_add, b_add, eras, addb);
  kQe<<<dim3(BSN / 32), 256, 0, stream>>>(q_data, q_table, key_mem, W_df1, b_df1,
                                          W_df2, b_df2, w_all, diffb, sinb);
  kScan<<<dim3(B_N), 512, 0, stream>>>(w_all, eras, addb, init_mem, sinb);
  kSum<<<dim3(BSN / 32, 4), 256, 0, stream>>>(sinb, W_sum, b_sum, summ);
  kAb<<<dim3(BSN / 32, 4), 256, 0, stream>>>(summ, W_ab1, b_ab1, W_ab2, part);
  kOut<<<dim3(BSN / 256), 256, 0, stream>>>(part, diffb, b_ab2, (float*)d_out);
}

// Round 4
// 664.370 us; speedup vs baseline: 2.7154x; 2.7154x over previous
//
#include <hip/hip_runtime.h>
#include <hip/hip_bf16.h>

typedef unsigned short u16;
typedef unsigned int   u32;

#define B_N   256
#define S_N   512
#define BSN   (B_N * S_N)      // 131072 positions
#define MEMN  32
#define DKN   128
#define DVN   128
#define DSN   256

typedef __attribute__((ext_vector_type(8))) short bf16x8;
typedef __attribute__((ext_vector_type(4))) float f32x4;

// ---------- helpers ----------
__device__ __forceinline__ float bf2f(u16 u) {
  union { u32 i; float f; } v; v.i = ((u32)u) << 16; return v.f;
}
__device__ __forceinline__ u16 f2bf(float f) {
  union { float f; u32 i; } v; v.f = f;
  u32 x = v.i;
  x += 0x7fffu + ((x >> 16) & 1u);   // RNE
  return (u16)(x >> 16);
}
__device__ __forceinline__ u32 pack2(float a, float b) {
  return (u32)f2bf(a) | ((u32)f2bf(b) << 16);
}
__device__ __forceinline__ float sigmoid_fast(float x) { return 1.f / (1.f + __expf(-x)); }
__device__ __forceinline__ float tanh_fast(float x)    { return 1.f - 2.f / (__expf(2.f * x) + 1.f); }

// ============================================================
// kPrep: transpose + bf16-convert weights.
// ============================================================
__global__ __launch_bounds__(256) void kPrep(
    const float* __restrict__ W_sum, const float* __restrict__ W_ab1,
    const float* __restrict__ W_er,  const float* __restrict__ W_ad,
    u16* __restrict__ WsumT, u16* __restrict__ Wab1T,
    u16* __restrict__ WerT,  u16* __restrict__ WaddT)
{
  int e = blockIdx.x * 256 + threadIdx.x;
  if (e < 65536) {
    const int n = e >> 8, k = e & 255;
    WsumT[e] = f2bf(W_sum[k * 256 + n]);
  } else if (e < 131072) {
    e -= 65536;
    const int n = e >> 8, k = e & 255;
    Wab1T[e] = f2bf(W_ab1[k * 256 + n]);
  } else if (e < 147456) {
    e -= 131072;
    const int n = e >> 7, k = e & 127;
    WerT[e] = f2bf(W_er[k * 128 + n]);
  } else {
    e -= 147456;
    const int n = e >> 7, k = e & 127;
    WaddT[e] = f2bf(W_ad[k * 128 + n]);
  }
}

// ============================================================
// kErAdd: MFMA GEMM. out = act(qae @ W + b), W pre-transposed bf16.
// grid (BSN/128, 2), block 256 (4 waves, 64x64 tiles). y: 0=erase, 1=add.
// ============================================================
__global__ __launch_bounds__(256) void kErAdd(
    const int* __restrict__ qa_data, const float* __restrict__ qa_table,
    const u16* __restrict__ WerT, const u16* __restrict__ WaddT,
    const float* __restrict__ b_er, const float* __restrict__ b_ad,
    u16* __restrict__ eras, u16* __restrict__ addb)
{
  __shared__ __align__(16) u16 As[4 * 128 * 32];   // [chunk][m][k'] 32 KB
  __shared__ __align__(16) u16 Bs[2 * 128 * 32];   // dbuf [n][k'] 16 KB
  const int tid = threadIdx.x;
  const int p0  = blockIdx.x * 128;
  const int sel = blockIdx.y;
  const u16*   Wt = sel ? WaddT : WerT;
  const float* bb = sel ? b_ad  : b_er;
  u16*       outp = sel ? addb  : eras;

  // ---- stage A: gather 128 rows of qa_table (f32 -> bf16), chunked layout
  {
    const int r = tid >> 1, h = tid & 1;
    const long base = (long)qa_data[p0 + r] * DVN + h * 64;
    #pragma unroll
    for (int g = 0; g < 8; ++g) {
      const int k0 = h * 64 + g * 8;
      const float4 fa = *(const float4*)(qa_table + base + g * 8);
      const float4 fb = *(const float4*)(qa_table + base + g * 8 + 4);
      uint4 pk;
      pk.x = pack2(fa.x, fa.y); pk.y = pack2(fa.z, fa.w);
      pk.z = pack2(fb.x, fb.y); pk.w = pack2(fb.z, fb.w);
      *(uint4*)(As + (k0 >> 5) * 4096 + r * 32 + (k0 & 31)) = pk;
    }
  }
  // ---- stage B chunk 0
  {
    #pragma unroll
    for (int u = 0; u < 2; ++u) {
      const int f = tid + 256 * u;           // 0..511
      const int n = f >> 2, j = f & 3;
      *(uint4*)(Bs + n * 32 + j * 8) = *(const uint4*)(Wt + n * 128 + j * 8);
    }
  }
  __syncthreads();

  const int lane = tid & 63, wave = tid >> 6;
  const int wr = (wave >> 1) * 64, wc = (wave & 1) * 64;
  const int c15 = lane & 15, q = lane >> 4;

  f32x4 acc[4][4];
  #pragma unroll
  for (int b = 0; b < 4; ++b) {
    const float bv = bb[wc + 16 * b + c15];
    #pragma unroll
    for (int a = 0; a < 4; ++a) acc[a][b] = (f32x4){bv, bv, bv, bv};
  }

  for (int c = 0; c < 4; ++c) {
    const int cur = c & 1;
    uint4 st[2];
    const bool more = (c + 1 < 4);
    if (more) {
      #pragma unroll
      for (int u = 0; u < 2; ++u) {
        const int f = tid + 256 * u;
        const int n = f >> 2, j = f & 3;
        st[u] = *(const uint4*)(Wt + n * 128 + (c + 1) * 32 + j * 8);
      }
    }
    bf16x8 af[4], bf[4];
    #pragma unroll
    for (int a = 0; a < 4; ++a)
      af[a] = *(const bf16x8*)(As + c * 4096 + (wr + 16 * a + c15) * 32 + q * 8);
    #pragma unroll
    for (int b = 0; b < 4; ++b)
      bf[b] = *(const bf16x8*)(Bs + cur * 4096 + (wc + 16 * b + c15) * 32 + q * 8);
    #pragma unroll
    for (int a = 0; a < 4; ++a)
      #pragma unroll
      for (int b = 0; b < 4; ++b)
        acc[a][b] = __builtin_amdgcn_mfma_f32_16x16x32_bf16(af[a], bf[b], acc[a][b], 0, 0, 0);
    if (more) {
      #pragma unroll
      for (int u = 0; u < 2; ++u) {
        const int f = tid + 256 * u;
        const int n = f >> 2, j = f & 3;
        *(uint4*)(Bs + (cur ^ 1) * 4096 + n * 32 + j * 8) = st[u];
      }
    }
    __syncthreads();
  }

  // ---- epilogue: activation + u16 stores
  const int colb = wc + c15;
  #pragma unroll
  for (int a = 0; a < 4; ++a) {
    #pragma unroll
    for (int r = 0; r < 4; ++r) {
      const int row = p0 + wr + 16 * a + 4 * q + r;
      u16* yp = outp + (long)row * DVN + colb;
      #pragma unroll
      for (int b = 0; b < 4; ++b) {
        const float v = sel ? tanh_fast(acc[a][b][r]) : sigmoid_fast(acc[a][b][r]);
        yp[16 * b] = f2bf(v);
      }
    }
  }
}

// ============================================================
// kSum: MFMA GEMM. summary = tanh(sin @ W_sum + b). K=256 (8 chunks).
// grid (BSN/128, 2: col half). LDS: A 64KB + B 16KB = 80KB.
// ============================================================
__global__ __launch_bounds__(256) void kSum(
    const u16* __restrict__ X, const u16* __restrict__ WsumT,
    const float* __restrict__ bias, u16* __restrict__ Y)
{
  __shared__ __align__(16) u16 As[8 * 128 * 32];   // 64 KB
  __shared__ __align__(16) u16 Bs[2 * 128 * 32];   // 16 KB
  const int tid = threadIdx.x;
  const int p0  = blockIdx.x * 128;
  const int j0  = blockIdx.y * 128;

  { // stage A (bf16 copy, chunked) — FULL K coverage: 4096 uint4
    #pragma unroll
    for (int u = 0; u < 16; ++u) {
      const int f = tid + 256 * u;           // 0..4095
      const int r = f >> 5, j = f & 31;      // r: row 0..127, j: k-octet 0..31
      const uint4 raw = *(const uint4*)(X + (long)(p0 + r) * DSN + j * 8);
      *(uint4*)(As + (j >> 2) * 4096 + r * 32 + (j & 3) * 8) = raw;
    }
  }
  { // stage B chunk 0
    #pragma unroll
    for (int u = 0; u < 2; ++u) {
      const int f = tid + 256 * u;
      const int n = f >> 2, j = f & 3;
      *(uint4*)(Bs + n * 32 + j * 8) = *(const uint4*)(WsumT + (j0 + n) * 256 + j * 8);
    }
  }
  __syncthreads();

  const int lane = tid & 63, wave = tid >> 6;
  const int wr = (wave >> 1) * 64, wc = (wave & 1) * 64;
  const int c15 = lane & 15, q = lane >> 4;

  f32x4 acc[4][4];
  #pragma unroll
  for (int b = 0; b < 4; ++b) {
    const float bv = bias[j0 + wc + 16 * b + c15];
    #pragma unroll
    for (int a = 0; a < 4; ++a) acc[a][b] = (f32x4){bv, bv, bv, bv};
  }

  for (int c = 0; c < 8; ++c) {
    const int cur = c & 1;
    uint4 st[2];
    const bool more = (c + 1 < 8);
    if (more) {
      #pragma unroll
      for (int u = 0; u < 2; ++u) {
        const int f = tid + 256 * u;
        const int n = f >> 2, j = f & 3;
        st[u] = *(const uint4*)(WsumT + (j0 + n) * 256 + (c + 1) * 32 + j * 8);
      }
    }
    bf16x8 af[4], bf[4];
    #pragma unroll
    for (int a = 0; a < 4; ++a)
      af[a] = *(const bf16x8*)(As + c * 4096 + (wr + 16 * a + c15) * 32 + q * 8);
    #pragma unroll
    for (int b = 0; b < 4; ++b)
      bf[b] = *(const bf16x8*)(Bs + cur * 4096 + (wc + 16 * b + c15) * 32 + q * 8);
    #pragma unroll
    for (int a = 0; a < 4; ++a)
      #pragma unroll
      for (int b = 0; b < 4; ++b)
        acc[a][b] = __builtin_amdgcn_mfma_f32_16x16x32_bf16(af[a], bf[b], acc[a][b], 0, 0, 0);
    if (more) {
      #pragma unroll
      for (int u = 0; u < 2; ++u) {
        const int f = tid + 256 * u;
        const int n = f >> 2, j = f & 3;
        *(uint4*)(Bs + (cur ^ 1) * 4096 + n * 32 + j * 8) = st[u];
      }
    }
    __syncthreads();
  }

  const int colb = j0 + wc + c15;
  #pragma unroll
  for (int a = 0; a < 4; ++a) {
    #pragma unroll
    for (int r = 0; r < 4; ++r) {
      const int row = p0 + wr + 16 * a + 4 * q + r;
      u16* yp = Y + (long)row * DSN + colb;
      #pragma unroll
      for (int b = 0; b < 4; ++b)
        yp[16 * b] = f2bf(tanh_fast(acc[a][b][r]));
    }
  }
}

// ============================================================
// kAb: MFMA GEMM + fused W_ab2 dot.
// part[y][p] = sum_{j in col half} tanh(summ@W_ab1+b)[j]*W_ab2[j]
// ============================================================
__global__ __launch_bounds__(256) void kAb(
    const u16* __restrict__ X, const u16* __restrict__ Wab1T,
    const float* __restrict__ bias, const float* __restrict__ Wab2,
    float* __restrict__ part)
{
  __shared__ __align__(16) u16 As[8 * 128 * 32];
  __shared__ __align__(16) u16 Bs[2 * 128 * 32];
  const int tid = threadIdx.x;
  const int p0  = blockIdx.x * 128;
  const int j0  = blockIdx.y * 128;

  { // stage A — FULL K coverage: 4096 uint4
    #pragma unroll
    for (int u = 0; u < 16; ++u) {
      const int f = tid + 256 * u;
      const int r = f >> 5, j = f & 31;
      const uint4 raw = *(const uint4*)(X + (long)(p0 + r) * DSN + j * 8);
      *(uint4*)(As + (j >> 2) * 4096 + r * 32 + (j & 3) * 8) = raw;
    }
  }
  {
    #pragma unroll
    for (int u = 0; u < 2; ++u) {
      const int f = tid + 256 * u;
      const int n = f >> 2, j = f & 3;
      *(uint4*)(Bs + n * 32 + j * 8) = *(const uint4*)(Wab1T + (j0 + n) * 256 + j * 8);
    }
  }
  __syncthreads();

  const int lane = tid & 63, wave = tid >> 6;
  const int wr = (wave >> 1) * 64, wc = (wave & 1) * 64;
  const int c15 = lane & 15, q = lane >> 4;

  f32x4 acc[4][4];
  float w2v[4];
  #pragma unroll
  for (int b = 0; b < 4; ++b) {
    const int col = j0 + wc + 16 * b + c15;
    const float bv = bias[col];
    w2v[b] = Wab2[col];
    #pragma unroll
    for (int a = 0; a < 4; ++a) acc[a][b] = (f32x4){bv, bv, bv, bv};
  }

  for (int c = 0; c < 8; ++c) {
    const int cur = c & 1;
    uint4 st[2];
    const bool more = (c + 1 < 8);
    if (more) {
      #pragma unroll
      for (int u = 0; u < 2; ++u) {
        const int f = tid + 256 * u;
        const int n = f >> 2, j = f & 3;
        st[u] = *(const uint4*)(Wab1T + (j0 + n) * 256 + (c + 1) * 32 + j * 8);
      }
    }
    bf16x8 af[4], bf[4];
    #pragma unroll
    for (int a = 0; a < 4; ++a)
      af[a] = *(const bf16x8*)(As + c * 4096 + (wr + 16 * a + c15) * 32 + q * 8);
    #pragma unroll
    for (int b = 0; b < 4; ++b)
      bf[b] = *(const bf16x8*)(Bs + cur * 4096 + (wc + 16 * b + c15) * 32 + q * 8);
    #pragma unroll
    for (int a = 0; a < 4; ++a)
      #pragma unroll
      for (int b = 0; b < 4; ++b)
        acc[a][b] = __builtin_amdgcn_mfma_f32_16x16x32_bf16(af[a], bf[b], acc[a][b], 0, 0, 0);
    if (more) {
      #pragma unroll
      for (int u = 0; u < 2; ++u) {
        const int f = tid + 256 * u;
        const int n = f >> 2, j = f & 3;
        *(uint4*)(Bs + (cur ^ 1) * 4096 + n * 32 + j * 8) = st[u];
      }
    }
    __syncthreads();   // final barrier also fences Bs reuse below
  }

  // ---- epilogue: tanh, dot with W_ab2, reduce 16 col-lanes, pair waves
  float sv[4][4];
  #pragma unroll
  for (int a = 0; a < 4; ++a) {
    #pragma unroll
    for (int r = 0; r < 4; ++r) {
      float s = 0.f;
      #pragma unroll
      for (int b = 0; b < 4; ++b)
        s = fmaf(tanh_fast(acc[a][b][r]), w2v[b], s);
      s += __shfl_xor(s, 1, 64);
      s += __shfl_xor(s, 2, 64);
      s += __shfl_xor(s, 4, 64);
      s += __shfl_xor(s, 8, 64);
      sv[a][r] = s;
    }
  }
  float* red = (float*)Bs;   // 128 f32, reuse (fenced by loop's last barrier)
  if ((wave & 1) && c15 == 0) {
    #pragma unroll
    for (int a = 0; a < 4; ++a)
      #pragma unroll
      for (int r = 0; r < 4; ++r)
        red[wr + 16 * a + 4 * q + r] = sv[a][r];
  }
  __syncthreads();
  if (!(wave & 1) && c15 == 0) {
    #pragma unroll
    for (int a = 0; a < 4; ++a)
      #pragma unroll
      for (int r = 0; r < 4; ++r) {
        const int rr = wr + 16 * a + 4 * q + r;
        part[(long)blockIdx.y * BSN + p0 + rr] = sv[a][r] + red[rr];
      }
  }
}

// ============================================================
// kQe: attention weights w (softmax), difficulty head, qe->summary-in copy
// grid (BSN/32), block 256   (unchanged)
// ============================================================
__global__ __launch_bounds__(256) void kQe(
    const int* __restrict__ q_data, const float* __restrict__ q_table,
    const float* __restrict__ key_mem,
    const float* __restrict__ Wdf1, const float* __restrict__ bdf1,
    const float* __restrict__ Wdf2, const float* __restrict__ bdf2,
    float* __restrict__ w_all, float* __restrict__ diff,
    u16* __restrict__ sin_buf)
{
  __shared__ __align__(16) float Wl[DKN * DKN];    // 64 KB
  __shared__ __align__(16) float Xt[DKN * 32];     // 16 KB
  __shared__ __align__(16) float Kt[DKN * 32];     // 16 KB; reused as H
  __shared__ int idx[32];
  const int tid = threadIdx.x;
  const int p0  = blockIdx.x * 32;

  if (tid < 32) idx[tid] = q_data[p0 + tid];
  {
    const float4* Wg = (const float4*)Wdf1;
    float4* Ws = (float4*)Wl;
    #pragma unroll
    for (int u = 0; u < 16; ++u) Ws[tid + 256 * u] = Wg[tid + 256 * u];
  }
  __syncthreads();
  {
    const int r = tid & 31, cb = tid >> 5;
    #pragma unroll
    for (int u = 0; u < 4; ++u) {
      const int k0 = cb * 16 + u * 4;
      const float4 raw = *(const float4*)(q_table + (long)idx[r] * DKN + k0);
      Xt[(k0 + 0) * 32 + r] = raw.x;
      Xt[(k0 + 1) * 32 + r] = raw.y;
      Xt[(k0 + 2) * 32 + r] = raw.z;
      Xt[(k0 + 3) * 32 + r] = raw.w;
    }
  }
  {
    const int m = tid & 31, cb = tid >> 5;
    #pragma unroll
    for (int u = 0; u < 4; ++u) {
      const int k0 = cb * 16 + u * 4;
      const float4 raw = *(const float4*)(key_mem + m * DKN + k0);
      Kt[(k0 + 0) * 32 + m] = raw.x;
      Kt[(k0 + 1) * 32 + m] = raw.y;
      Kt[(k0 + 2) * 32 + m] = raw.z;
      Kt[(k0 + 3) * 32 + m] = raw.w;
    }
  }
  __syncthreads();

  {
    const int pos = tid >> 3;
    const int m4  = (tid & 7) * 4;
    float s0 = 0.f, s1 = 0.f, s2 = 0.f, s3 = 0.f;
    #pragma unroll 4
    for (int k = 0; k < DKN; ++k) {
      const float x = Xt[k * 32 + pos];
      const float4 kv = *(const float4*)(Kt + k * 32 + m4);
      s0 = fmaf(x, kv.x, s0);
      s1 = fmaf(x, kv.y, s1);
      s2 = fmaf(x, kv.z, s2);
      s3 = fmaf(x, kv.w, s3);
    }
    float mx = fmaxf(fmaxf(s0, s1), fmaxf(s2, s3));
    #pragma unroll
    for (int d = 1; d <= 4; d <<= 1) mx = fmaxf(mx, __shfl_xor(mx, d, 64));
    const float e0 = __expf(s0 - mx), e1 = __expf(s1 - mx);
    const float e2 = __expf(s2 - mx), e3 = __expf(s3 - mx);
    float sm = e0 + e1 + e2 + e3;
    #pragma unroll
    for (int d = 1; d <= 4; d <<= 1) sm += __shfl_xor(sm, d, 64);
    const float inv = 1.f / sm;
    const float4 wv = make_float4(e0 * inv, e1 * inv, e2 * inv, e3 * inv);
    *(float4*)(w_all + (long)(p0 + pos) * MEMN + m4) = wv;
  }
  __syncthreads();

  const int jp = tid & 63;
  const int rg = tid >> 6;
  {
    float acc0[8], acc1[8];
    const float bv0 = bdf1[2 * jp], bv1 = bdf1[2 * jp + 1];
    #pragma unroll
    for (int i = 0; i < 8; ++i) { acc0[i] = bv0; acc1[i] = bv1; }
    #pragma unroll 4
    for (int k = 0; k < DKN; ++k) {
      const float2 wp = *(const float2*)(Wl + k * DKN + 2 * jp);
      const float4 xa = *(const float4*)(Xt + k * 32 + rg * 8);
      const float4 xb = *(const float4*)(Xt + k * 32 + rg * 8 + 4);
      const float xs[8] = {xa.x, xa.y, xa.z, xa.w, xb.x, xb.y, xb.z, xb.w};
      #pragma unroll
      for (int i = 0; i < 8; ++i) {
        acc0[i] = fmaf(xs[i], wp.x, acc0[i]);
        acc1[i] = fmaf(xs[i], wp.y, acc1[i]);
      }
    }
    float* H = Kt;
    #pragma unroll
    for (int i = 0; i < 8; ++i) {
      const int r = rg * 8 + i;
      H[r * DKN + 2 * jp]     = tanh_fast(acc0[i]);
      H[r * DKN + 2 * jp + 1] = tanh_fast(acc1[i]);
    }
  }
  __syncthreads();

  {
    const float* H = Kt;
    const int wv   = tid >> 6;
    const int lane = tid & 63;
    const float w2a = Wdf2[lane], w2b = Wdf2[64 + lane];
    const float bd  = bdf2[0];
    #pragma unroll
    for (int r8 = 0; r8 < 8; ++r8) {
      const int r = wv * 8 + r8;
      float sgm = H[r * DKN + lane] * w2a + H[r * DKN + 64 + lane] * w2b;
      #pragma unroll
      for (int d = 1; d < 64; d <<= 1) sgm += __shfl_xor(sgm, d, 64);
      if (lane == 0) diff[p0 + r] = sgm + bd;
    }
  }

  {
    #pragma unroll
    for (int u = 0; u < 4; ++u) {
      const int c = tid + 256 * u;
      const int r = c >> 5, k0 = (c & 31) * 4;
      const float4 raw = *(const float4*)(q_table + (long)idx[r] * DKN + k0);
      uint2 two;
      two.x = pack2(raw.x, raw.y);
      two.y = pack2(raw.z, raw.w);
      *(uint2*)(sin_buf + (long)(p0 + r) * DSN + DKN + k0) = two;
    }
  }
}

// ============================================================
// kScan: sequential DKVMN recurrence (unchanged)
// ============================================================
__global__ __launch_bounds__(512) void kScan(
    const float* __restrict__ w_all, const u16* __restrict__ eras,
    const u16* __restrict__ addb, const float* __restrict__ init_mem,
    u16* __restrict__ sin_buf)
{
  const int tid = threadIdx.x;
  const int c = tid >> 2;
  const int q = tid & 3;
  float Mv[8];
  #pragma unroll
  for (int i = 0; i < 8; ++i) Mv[i] = init_mem[(q * 8 + i) * DVN + c];

  int p = blockIdx.x * S_N;
  float4 wA = *(const float4*)(w_all + (long)p * MEMN + q * 8);
  float4 wB = *(const float4*)(w_all + (long)p * MEMN + q * 8 + 4);
  float ec = bf2f(eras[(long)p * DVN + c]);
  float ac = bf2f(addb[(long)p * DVN + c]);

  for (int s = 0; s < S_N; ++s, ++p) {
    const int pn = (s == S_N - 1) ? p : p + 1;
    const float4 wAn = *(const float4*)(w_all + (long)pn * MEMN + q * 8);
    const float4 wBn = *(const float4*)(w_all + (long)pn * MEMN + q * 8 + 4);
    const u16 en = eras[(long)pn * DVN + c];
    const u16 an = addb[(long)pn * DVN + c];

    const float wr[8] = {wA.x, wA.y, wA.z, wA.w, wB.x, wB.y, wB.z, wB.w};
    float pr = 0.f;
    #pragma unroll
    for (int i = 0; i < 8; ++i) pr = fmaf(wr[i], Mv[i], pr);
    pr += __shfl_xor(pr, 1, 64);
    pr += __shfl_xor(pr, 2, 64);
    if (q == 0) sin_buf[(long)p * DSN + c] = f2bf(pr);
    #pragma unroll
    for (int i = 0; i < 8; ++i) {
      const float t1 = wr[i] * ec;
      const float u  = fmaf(wr[i], ac, Mv[i]);
      Mv[i] = fmaf(-Mv[i], t1, u);
    }
    wA = wAn; wB = wBn; ec = bf2f(en); ac = bf2f(an);
  }
}

// ============================================================
// kOut: combine. grid (BSN/256), block 256. f32 output.
// ============================================================
__global__ __launch_bounds__(256) void kOut(
    const float* __restrict__ part, const float* __restrict__ diff,
    const float* __restrict__ bab2, float* __restrict__ out)
{
  const int p = blockIdx.x * 256 + threadIdx.x;
  const float ab = part[p] + part[BSN + p] + bab2[0];
  const float d  = diff[p];
  const float z  = 3.0f * ab - d;
  out[p]           = sigmoid_fast(z);
  out[BSN + p]     = ab;
  out[2 * BSN + p] = d;
  out[3 * BSN + p] = z;
}

// ============================================================
// launch
// ============================================================
extern "C" void kernel_launch(void* const* d_in, const int* in_sizes, int n_in,
                              void* d_out, int out_size, void* d_ws, size_t ws_size,
                              hipStream_t stream)
{
  const int*   q_data   = (const int*)d_in[0];
  const int*   qa_data  = (const int*)d_in[1];
  const float* q_table  = (const float*)d_in[2];
  const float* qa_table = (const float*)d_in[3];
  const float* key_mem  = (const float*)d_in[4];
  const float* init_mem = (const float*)d_in[5];
  const float* W_erase  = (const float*)d_in[6];
  const float* b_erase  = (const float*)d_in[7];
  const float* W_add    = (const float*)d_in[8];
  const float* b_add    = (const float*)d_in[9];
  const float* W_sum    = (const float*)d_in[10];
  const float* b_sum    = (const float*)d_in[11];
  const float* W_ab1    = (const float*)d_in[12];
  const float* b_ab1    = (const float*)d_in[13];
  const float* W_ab2    = (const float*)d_in[14];
  const float* b_ab2    = (const float*)d_in[15];
  const float* W_df1    = (const float*)d_in[16];
  const float* b_df1    = (const float*)d_in[17];
  const float* W_df2    = (const float*)d_in[18];
  const float* b_df2    = (const float*)d_in[19];

  // workspace layout (bytes); total 152,895,488
  char* ws = (char*)d_ws;
  float* w_all = (float*)(ws + 0);           // [BS][32] f32   16,777,216
  u16*   eras  = (u16*)(ws + 16777216);      // [BS][128] bf16 33,554,432
  u16*   addb  = (u16*)(ws + 50331648);      // [BS][128] bf16 33,554,432
  u16*   sinb  = (u16*)(ws + 83886080);      // [BS][256] bf16 67,108,864
  float* diffb = (float*)(ws + 150994944);   // [BS] f32          524,288
  float* part  = (float*)(ws + 151519232);   // [2][BS] f32     1,048,576
  u16*   WerT  = (u16*)(ws + 152567808);     // 32,768
  u16*   WaddT = (u16*)(ws + 152600576);     // 32,768
  u16*   WsumT = (u16*)(ws + 152633344);     // 131,072
  u16*   Wab1T = (u16*)(ws + 152764416);     // 131,072
  u16*   summ  = eras;                       // summary reuses eras+addb

  kPrep<<<dim3(640), 256, 0, stream>>>(W_sum, W_ab1, W_erase, W_add,
                                       WsumT, Wab1T, WerT, WaddT);
  kErAdd<<<dim3(BSN / 128, 2), 256, 0, stream>>>(qa_data, qa_table, WerT, WaddT,
                                                 b_erase, b_add, eras, addb);
  kQe<<<dim3(BSN / 32), 256, 0, stream>>>(q_data, q_table, key_mem, W_df1, b_df1,
                                          W_df2, b_df2, w_all, diffb, sinb);
  kScan<<<dim3(B_N), 512, 0, stream>>>(w_all, eras, addb, init_mem, sinb);
  kSum<<<dim3(BSN / 128, 2), 256, 0, stream>>>(sinb, WsumT, b_sum, summ);
  kAb<<<dim3(BSN / 128, 2), 256, 0, stream>>>(summ, Wab1T, b_ab1, W_ab2, part);
  kOut<<<dim3(BSN / 256), 256, 0, stream>>>(part, diffb, b_ab2, (float*)d_out);
}

// Round 5
// 501.639 us; speedup vs baseline: 3.5963x; 1.3244x over previous
//
#include <hip/hip_runtime.h>
#include <hip/hip_bf16.h>

typedef unsigned short u16;
typedef unsigned int   u32;

#define B_N   256
#define S_N   512
#define BSN   (B_N * S_N)      // 131072 positions
#define MEMN  32
#define DKN   128
#define DVN   128
#define DSN   256

typedef __attribute__((ext_vector_type(8))) short bf16x8;
typedef __attribute__((ext_vector_type(4))) float f32x4;

// ---------- helpers ----------
__device__ __forceinline__ float bf2f(u16 u) {
  union { u32 i; float f; } v; v.i = ((u32)u) << 16; return v.f;
}
__device__ __forceinline__ u16 f2bf(float f) {
  union { float f; u32 i; } v; v.f = f;
  u32 x = v.i;
  x += 0x7fffu + ((x >> 16) & 1u);   // RNE
  return (u16)(x >> 16);
}
__device__ __forceinline__ u32 pack2(float a, float b) {
  return (u32)f2bf(a) | ((u32)f2bf(b) << 16);
}
__device__ __forceinline__ float sigmoid_fast(float x) { return 1.f / (1.f + __expf(-x)); }
__device__ __forceinline__ float tanh_fast(float x)    { return 1.f - 2.f / (__expf(2.f * x) + 1.f); }

// ============================================================
// kPrep: transpose + bf16-convert weights; build concatenated BqT:
// BqT[n][k], n<32: key_mem[n][k]; n>=32: W_df1[k][n-32].   184320 elems.
// ============================================================
__global__ __launch_bounds__(256) void kPrep(
    const float* __restrict__ W_sum, const float* __restrict__ W_ab1,
    const float* __restrict__ W_er,  const float* __restrict__ W_ad,
    const float* __restrict__ key_mem, const float* __restrict__ W_df1,
    u16* __restrict__ WsumT, u16* __restrict__ Wab1T,
    u16* __restrict__ WerT,  u16* __restrict__ WaddT,
    u16* __restrict__ BqT)
{
  int e = blockIdx.x * 256 + threadIdx.x;
  if (e < 65536) {
    const int n = e >> 8, k = e & 255;
    WsumT[e] = f2bf(W_sum[k * 256 + n]);
  } else if (e < 131072) {
    e -= 65536;
    const int n = e >> 8, k = e & 255;
    Wab1T[e] = f2bf(W_ab1[k * 256 + n]);
  } else if (e < 147456) {
    e -= 131072;
    const int n = e >> 7, k = e & 127;
    WerT[e] = f2bf(W_er[k * 128 + n]);
  } else if (e < 163840) {
    e -= 147456;
    const int n = e >> 7, k = e & 127;
    WaddT[e] = f2bf(W_ad[k * 128 + n]);
  } else if (e < 184320) {
    e -= 163840;
    const int n = e >> 7, k = e & 127;
    BqT[e] = f2bf(n < 32 ? key_mem[n * 128 + k] : W_df1[k * 128 + (n - 32)]);
  }
}

// ============================================================
// kErAdd: MFMA GEMM. out = act(qae @ W + b), W pre-transposed bf16.
// grid (BSN/128, 2), block 256 (4 waves, 64x64 tiles). y: 0=erase, 1=add.
// ============================================================
__global__ __launch_bounds__(256) void kErAdd(
    const int* __restrict__ qa_data, const float* __restrict__ qa_table,
    const u16* __restrict__ WerT, const u16* __restrict__ WaddT,
    const float* __restrict__ b_er, const float* __restrict__ b_ad,
    u16* __restrict__ eras, u16* __restrict__ addb)
{
  __shared__ __align__(16) u16 As[4 * 128 * 32];   // [chunk][m][k'] 32 KB
  __shared__ __align__(16) u16 Bs[2 * 128 * 32];   // dbuf [n][k'] 16 KB
  const int tid = threadIdx.x;
  const int p0  = blockIdx.x * 128;
  const int sel = blockIdx.y;
  const u16*   Wt = sel ? WaddT : WerT;
  const float* bb = sel ? b_ad  : b_er;
  u16*       outp = sel ? addb  : eras;

  // ---- stage A: gather 128 rows of qa_table (f32 -> bf16), chunked layout
  {
    const int r = tid >> 1, h = tid & 1;
    const long base = (long)qa_data[p0 + r] * DVN + h * 64;
    #pragma unroll
    for (int g = 0; g < 8; ++g) {
      const int k0 = h * 64 + g * 8;
      const float4 fa = *(const float4*)(qa_table + base + g * 8);
      const float4 fb = *(const float4*)(qa_table + base + g * 8 + 4);
      uint4 pk;
      pk.x = pack2(fa.x, fa.y); pk.y = pack2(fa.z, fa.w);
      pk.z = pack2(fb.x, fb.y); pk.w = pack2(fb.z, fb.w);
      *(uint4*)(As + (k0 >> 5) * 4096 + r * 32 + (k0 & 31)) = pk;
    }
  }
  // ---- stage B chunk 0
  {
    #pragma unroll
    for (int u = 0; u < 2; ++u) {
      const int f = tid + 256 * u;           // 0..511
      const int n = f >> 2, j = f & 3;
      *(uint4*)(Bs + n * 32 + j * 8) = *(const uint4*)(Wt + n * 128 + j * 8);
    }
  }
  __syncthreads();

  const int lane = tid & 63, wave = tid >> 6;
  const int wr = (wave >> 1) * 64, wc = (wave & 1) * 64;
  const int c15 = lane & 15, q = lane >> 4;

  f32x4 acc[4][4];
  #pragma unroll
  for (int b = 0; b < 4; ++b) {
    const float bv = bb[wc + 16 * b + c15];
    #pragma unroll
    for (int a = 0; a < 4; ++a) acc[a][b] = (f32x4){bv, bv, bv, bv};
  }

  for (int c = 0; c < 4; ++c) {
    const int cur = c & 1;
    uint4 st[2];
    const bool more = (c + 1 < 4);
    if (more) {
      #pragma unroll
      for (int u = 0; u < 2; ++u) {
        const int f = tid + 256 * u;
        const int n = f >> 2, j = f & 3;
        st[u] = *(const uint4*)(Wt + n * 128 + (c + 1) * 32 + j * 8);
      }
    }
    bf16x8 af[4], bf[4];
    #pragma unroll
    for (int a = 0; a < 4; ++a)
      af[a] = *(const bf16x8*)(As + c * 4096 + (wr + 16 * a + c15) * 32 + q * 8);
    #pragma unroll
    for (int b = 0; b < 4; ++b)
      bf[b] = *(const bf16x8*)(Bs + cur * 4096 + (wc + 16 * b + c15) * 32 + q * 8);
    #pragma unroll
    for (int a = 0; a < 4; ++a)
      #pragma unroll
      for (int b = 0; b < 4; ++b)
        acc[a][b] = __builtin_amdgcn_mfma_f32_16x16x32_bf16(af[a], bf[b], acc[a][b], 0, 0, 0);
    if (more) {
      #pragma unroll
      for (int u = 0; u < 2; ++u) {
        const int f = tid + 256 * u;
        const int n = f >> 2, j = f & 3;
        *(uint4*)(Bs + (cur ^ 1) * 4096 + n * 32 + j * 8) = st[u];
      }
    }
    __syncthreads();
  }

  // ---- epilogue: activation + u16 stores
  const int colb = wc + c15;
  #pragma unroll
  for (int a = 0; a < 4; ++a) {
    #pragma unroll
    for (int r = 0; r < 4; ++r) {
      const int row = p0 + wr + 16 * a + 4 * q + r;
      u16* yp = outp + (long)row * DVN + colb;
      #pragma unroll
      for (int b = 0; b < 4; ++b) {
        const float v = sel ? tanh_fast(acc[a][b][r]) : sigmoid_fast(acc[a][b][r]);
        yp[16 * b] = f2bf(v);
      }
    }
  }
}

// ============================================================
// kSum: MFMA GEMM. summary = tanh(sin @ W_sum + b). K=256 (8 chunks).
// grid (BSN/128, 2: col half). LDS: A 64KB + B 16KB = 80KB.
// ============================================================
__global__ __launch_bounds__(256) void kSum(
    const u16* __restrict__ X, const u16* __restrict__ WsumT,
    const float* __restrict__ bias, u16* __restrict__ Y)
{
  __shared__ __align__(16) u16 As[8 * 128 * 32];   // 64 KB
  __shared__ __align__(16) u16 Bs[2 * 128 * 32];   // 16 KB
  const int tid = threadIdx.x;
  const int p0  = blockIdx.x * 128;
  const int j0  = blockIdx.y * 128;

  { // stage A (bf16 copy, chunked) — FULL K coverage: 4096 uint4
    #pragma unroll
    for (int u = 0; u < 16; ++u) {
      const int f = tid + 256 * u;           // 0..4095
      const int r = f >> 5, j = f & 31;      // r: row 0..127, j: k-octet 0..31
      const uint4 raw = *(const uint4*)(X + (long)(p0 + r) * DSN + j * 8);
      *(uint4*)(As + (j >> 2) * 4096 + r * 32 + (j & 3) * 8) = raw;
    }
  }
  { // stage B chunk 0
    #pragma unroll
    for (int u = 0; u < 2; ++u) {
      const int f = tid + 256 * u;
      const int n = f >> 2, j = f & 3;
      *(uint4*)(Bs + n * 32 + j * 8) = *(const uint4*)(WsumT + (j0 + n) * 256 + j * 8);
    }
  }
  __syncthreads();

  const int lane = tid & 63, wave = tid >> 6;
  const int wr = (wave >> 1) * 64, wc = (wave & 1) * 64;
  const int c15 = lane & 15, q = lane >> 4;

  f32x4 acc[4][4];
  #pragma unroll
  for (int b = 0; b < 4; ++b) {
    const float bv = bias[j0 + wc + 16 * b + c15];
    #pragma unroll
    for (int a = 0; a < 4; ++a) acc[a][b] = (f32x4){bv, bv, bv, bv};
  }

  for (int c = 0; c < 8; ++c) {
    const int cur = c & 1;
    uint4 st[2];
    const bool more = (c + 1 < 8);
    if (more) {
      #pragma unroll
      for (int u = 0; u < 2; ++u) {
        const int f = tid + 256 * u;
        const int n = f >> 2, j = f & 3;
        st[u] = *(const uint4*)(WsumT + (j0 + n) * 256 + (c + 1) * 32 + j * 8);
      }
    }
    bf16x8 af[4], bf[4];
    #pragma unroll
    for (int a = 0; a < 4; ++a)
      af[a] = *(const bf16x8*)(As + c * 4096 + (wr + 16 * a + c15) * 32 + q * 8);
    #pragma unroll
    for (int b = 0; b < 4; ++b)
      bf[b] = *(const bf16x8*)(Bs + cur * 4096 + (wc + 16 * b + c15) * 32 + q * 8);
    #pragma unroll
    for (int a = 0; a < 4; ++a)
      #pragma unroll
      for (int b = 0; b < 4; ++b)
        acc[a][b] = __builtin_amdgcn_mfma_f32_16x16x32_bf16(af[a], bf[b], acc[a][b], 0, 0, 0);
    if (more) {
      #pragma unroll
      for (int u = 0; u < 2; ++u) {
        const int f = tid + 256 * u;
        const int n = f >> 2, j = f & 3;
        *(uint4*)(Bs + (cur ^ 1) * 4096 + n * 32 + j * 8) = st[u];
      }
    }
    __syncthreads();
  }

  const int colb = j0 + wc + c15;
  #pragma unroll
  for (int a = 0; a < 4; ++a) {
    #pragma unroll
    for (int r = 0; r < 4; ++r) {
      const int row = p0 + wr + 16 * a + 4 * q + r;
      u16* yp = Y + (long)row * DSN + colb;
      #pragma unroll
      for (int b = 0; b < 4; ++b)
        yp[16 * b] = f2bf(tanh_fast(acc[a][b][r]));
    }
  }
}

// ============================================================
// kAb: MFMA GEMM + fused W_ab2 dot.
// ============================================================
__global__ __launch_bounds__(256) void kAb(
    const u16* __restrict__ X, const u16* __restrict__ Wab1T,
    const float* __restrict__ bias, const float* __restrict__ Wab2,
    float* __restrict__ part)
{
  __shared__ __align__(16) u16 As[8 * 128 * 32];
  __shared__ __align__(16) u16 Bs[2 * 128 * 32];
  const int tid = threadIdx.x;
  const int p0  = blockIdx.x * 128;
  const int j0  = blockIdx.y * 128;

  { // stage A — FULL K coverage: 4096 uint4
    #pragma unroll
    for (int u = 0; u < 16; ++u) {
      const int f = tid + 256 * u;
      const int r = f >> 5, j = f & 31;
      const uint4 raw = *(const uint4*)(X + (long)(p0 + r) * DSN + j * 8);
      *(uint4*)(As + (j >> 2) * 4096 + r * 32 + (j & 3) * 8) = raw;
    }
  }
  {
    #pragma unroll
    for (int u = 0; u < 2; ++u) {
      const int f = tid + 256 * u;
      const int n = f >> 2, j = f & 3;
      *(uint4*)(Bs + n * 32 + j * 8) = *(const uint4*)(Wab1T + (j0 + n) * 256 + j * 8);
    }
  }
  __syncthreads();

  const int lane = tid & 63, wave = tid >> 6;
  const int wr = (wave >> 1) * 64, wc = (wave & 1) * 64;
  const int c15 = lane & 15, q = lane >> 4;

  f32x4 acc[4][4];
  float w2v[4];
  #pragma unroll
  for (int b = 0; b < 4; ++b) {
    const int col = j0 + wc + 16 * b + c15;
    const float bv = bias[col];
    w2v[b] = Wab2[col];
    #pragma unroll
    for (int a = 0; a < 4; ++a) acc[a][b] = (f32x4){bv, bv, bv, bv};
  }

  for (int c = 0; c < 8; ++c) {
    const int cur = c & 1;
    uint4 st[2];
    const bool more = (c + 1 < 8);
    if (more) {
      #pragma unroll
      for (int u = 0; u < 2; ++u) {
        const int f = tid + 256 * u;
        const int n = f >> 2, j = f & 3;
        st[u] = *(const uint4*)(Wab1T + (j0 + n) * 256 + (c + 1) * 32 + j * 8);
      }
    }
    bf16x8 af[4], bf[4];
    #pragma unroll
    for (int a = 0; a < 4; ++a)
      af[a] = *(const bf16x8*)(As + c * 4096 + (wr + 16 * a + c15) * 32 + q * 8);
    #pragma unroll
    for (int b = 0; b < 4; ++b)
      bf[b] = *(const bf16x8*)(Bs + cur * 4096 + (wc + 16 * b + c15) * 32 + q * 8);
    #pragma unroll
    for (int a = 0; a < 4; ++a)
      #pragma unroll
      for (int b = 0; b < 4; ++b)
        acc[a][b] = __builtin_amdgcn_mfma_f32_16x16x32_bf16(af[a], bf[b], acc[a][b], 0, 0, 0);
    if (more) {
      #pragma unroll
      for (int u = 0; u < 2; ++u) {
        const int f = tid + 256 * u;
        const int n = f >> 2, j = f & 3;
        *(uint4*)(Bs + (cur ^ 1) * 4096 + n * 32 + j * 8) = st[u];
      }
    }
    __syncthreads();   // final barrier also fences Bs reuse below
  }

  // ---- epilogue: tanh, dot with W_ab2, reduce 16 col-lanes, pair waves
  float sv[4][4];
  #pragma unroll
  for (int a = 0; a < 4; ++a) {
    #pragma unroll
    for (int r = 0; r < 4; ++r) {
      float s = 0.f;
      #pragma unroll
      for (int b = 0; b < 4; ++b)
        s = fmaf(tanh_fast(acc[a][b][r]), w2v[b], s);
      s += __shfl_xor(s, 1, 64);
      s += __shfl_xor(s, 2, 64);
      s += __shfl_xor(s, 4, 64);
      s += __shfl_xor(s, 8, 64);
      sv[a][r] = s;
    }
  }
  float* red = (float*)Bs;   // 128 f32, reuse (fenced by loop's last barrier)
  if ((wave & 1) && c15 == 0) {
    #pragma unroll
    for (int a = 0; a < 4; ++a)
      #pragma unroll
      for (int r = 0; r < 4; ++r)
        red[wr + 16 * a + 4 * q + r] = sv[a][r];
  }
  __syncthreads();
  if (!(wave & 1) && c15 == 0) {
    #pragma unroll
    for (int a = 0; a < 4; ++a)
      #pragma unroll
      for (int r = 0; r < 4; ++r) {
        const int rr = wr + 16 * a + 4 * q + r;
        part[(long)blockIdx.y * BSN + p0 + rr] = sv[a][r] + red[rr];
      }
  }
}

// ============================================================
// kQe (MFMA): one GEMM qe[128x128] @ BqT^T[128x160] per block.
// cols 0..31 = attention scores -> softmax -> w_all
// cols 32..159 = df hidden -> tanh -> dot W_df2 -> diff
// qe -> sinb copy fused into A staging.
// grid (BSN/128), block 256 (4 waves: 2x2 of 64 rows x 80 cols).
// LDS: As 32KB + Bs 40KB = 72KB -> 2 blocks/CU.
// ============================================================
__global__ __launch_bounds__(256) void kQe(
    const int* __restrict__ q_data, const float* __restrict__ q_table,
    const u16* __restrict__ BqT,
    const float* __restrict__ bdf1, const float* __restrict__ Wdf2,
    const float* __restrict__ bdf2,
    float* __restrict__ w_all, float* __restrict__ diff,
    u16* __restrict__ sin_buf)
{
  __shared__ __align__(16) u16 As[4 * 128 * 32];   // 32 KB [chunk][row][k']
  __shared__ __align__(16) u16 Bs[4 * 160 * 32];   // 40 KB [chunk][n][k']
  const int tid = threadIdx.x;
  const int p0  = blockIdx.x * 128;

  // ---- stage A: gather qe rows (f32->bf16), fused sinb store
  {
    const int r = tid >> 1, h = tid & 1;
    const long base = (long)q_data[p0 + r] * DKN + h * 64;
    #pragma unroll
    for (int g = 0; g < 8; ++g) {
      const int k0 = h * 64 + g * 8;
      const float4 fa = *(const float4*)(q_table + base + g * 8);
      const float4 fb = *(const float4*)(q_table + base + g * 8 + 4);
      uint4 pk;
      pk.x = pack2(fa.x, fa.y); pk.y = pack2(fa.z, fa.w);
      pk.z = pack2(fb.x, fb.y); pk.w = pack2(fb.z, fb.w);
      *(uint4*)(As + (k0 >> 5) * 4096 + r * 32 + (k0 & 31)) = pk;
      *(uint4*)(sin_buf + (long)(p0 + r) * DSN + DKN + k0) = pk;
    }
  }
  // ---- stage B: 160 rows x 128 k = 2560 uint4 (10/thread)
  {
    #pragma unroll
    for (int u = 0; u < 10; ++u) {
      const int f = tid + 256 * u;           // 0..2559
      const int n = f >> 4, jj = f & 15;
      *(uint4*)(Bs + (jj >> 2) * 5120 + n * 32 + (jj & 3) * 8) =
          *(const uint4*)(BqT + n * 128 + jj * 8);
    }
  }
  __syncthreads();

  const int lane = tid & 63, wave = tid >> 6;
  const int wr = (wave >> 1) * 64, wc = (wave & 1) * 80;
  const int c15 = lane & 15, q = lane >> 4;

  f32x4 acc[4][5];
  float w2v[5];
  #pragma unroll
  for (int b = 0; b < 5; ++b) {
    const int col = wc + 16 * b + c15;
    const float bv = (col < 32) ? 0.f : bdf1[col - 32];
    w2v[b] = (col < 32) ? 0.f : Wdf2[col - 32];
    #pragma unroll
    for (int a = 0; a < 4; ++a) acc[a][b] = (f32x4){bv, bv, bv, bv};
  }

  #pragma unroll
  for (int c = 0; c < 4; ++c) {
    bf16x8 af[4], bf[5];
    #pragma unroll
    for (int a = 0; a < 4; ++a)
      af[a] = *(const bf16x8*)(As + c * 4096 + (wr + 16 * a + c15) * 32 + q * 8);
    #pragma unroll
    for (int b = 0; b < 5; ++b)
      bf[b] = *(const bf16x8*)(Bs + c * 5120 + (wc + 16 * b + c15) * 32 + q * 8);
    #pragma unroll
    for (int a = 0; a < 4; ++a)
      #pragma unroll
      for (int b = 0; b < 5; ++b)
        acc[a][b] = __builtin_amdgcn_mfma_f32_16x16x32_bf16(af[a], bf[b], acc[a][b], 0, 0, 0);
  }

  // ---- softmax over cols 0..31 (waves with wc==0 only: b=0,1)
  if (wc == 0) {
    #pragma unroll
    for (int a = 0; a < 4; ++a) {
      #pragma unroll
      for (int r = 0; r < 4; ++r) {
        float s0 = acc[a][0][r], s1 = acc[a][1][r];
        float mx = fmaxf(s0, s1);
        mx = fmaxf(mx, __shfl_xor(mx, 1, 64));
        mx = fmaxf(mx, __shfl_xor(mx, 2, 64));
        mx = fmaxf(mx, __shfl_xor(mx, 4, 64));
        mx = fmaxf(mx, __shfl_xor(mx, 8, 64));
        const float e0 = __expf(s0 - mx), e1 = __expf(s1 - mx);
        float sm = e0 + e1;
        sm += __shfl_xor(sm, 1, 64);
        sm += __shfl_xor(sm, 2, 64);
        sm += __shfl_xor(sm, 4, 64);
        sm += __shfl_xor(sm, 8, 64);
        const float inv = 1.f / sm;
        const int row = p0 + wr + 16 * a + 4 * q + r;
        w_all[(long)row * MEMN + c15]      = e0 * inv;
        w_all[(long)row * MEMN + 16 + c15] = e1 * inv;
      }
    }
  }

  // ---- diff partials: tanh + W_df2 dot (w2v==0 masks attention cols)
  float sv[4][4];
  #pragma unroll
  for (int a = 0; a < 4; ++a) {
    #pragma unroll
    for (int r = 0; r < 4; ++r) {
      float s = 0.f;
      #pragma unroll
      for (int b = 0; b < 5; ++b)
        s = fmaf(tanh_fast(acc[a][b][r]), w2v[b], s);
      s += __shfl_xor(s, 1, 64);
      s += __shfl_xor(s, 2, 64);
      s += __shfl_xor(s, 4, 64);
      s += __shfl_xor(s, 8, 64);
      sv[a][r] = s;
    }
  }
  __syncthreads();               // all MFMA LDS reads done; reuse As
  float* red = (float*)As;       // 128 f32
  if ((wave & 1) && c15 == 0) {  // wc==80 waves
    #pragma unroll
    for (int a = 0; a < 4; ++a)
      #pragma unroll
      for (int r = 0; r < 4; ++r)
        red[wr + 16 * a + 4 * q + r] = sv[a][r];
  }
  __syncthreads();
  if (!(wave & 1) && c15 == 0) {
    const float bd = bdf2[0];
    #pragma unroll
    for (int a = 0; a < 4; ++a)
      #pragma unroll
      for (int r = 0; r < 4; ++r) {
        const int rr = wr + 16 * a + 4 * q + r;
        diff[p0 + rr] = sv[a][r] + red[rr] + bd;
      }
  }
}

// ============================================================
// kScan: sequential DKVMN recurrence (unchanged)
// ============================================================
__global__ __launch_bounds__(512) void kScan(
    const float* __restrict__ w_all, const u16* __restrict__ eras,
    const u16* __restrict__ addb, const float* __restrict__ init_mem,
    u16* __restrict__ sin_buf)
{
  const int tid = threadIdx.x;
  const int c = tid >> 2;
  const int q = tid & 3;
  float Mv[8];
  #pragma unroll
  for (int i = 0; i < 8; ++i) Mv[i] = init_mem[(q * 8 + i) * DVN + c];

  int p = blockIdx.x * S_N;
  float4 wA = *(const float4*)(w_all + (long)p * MEMN + q * 8);
  float4 wB = *(const float4*)(w_all + (long)p * MEMN + q * 8 + 4);
  float ec = bf2f(eras[(long)p * DVN + c]);
  float ac = bf2f(addb[(long)p * DVN + c]);

  for (int s = 0; s < S_N; ++s, ++p) {
    const int pn = (s == S_N - 1) ? p : p + 1;
    const float4 wAn = *(const float4*)(w_all + (long)pn * MEMN + q * 8);
    const float4 wBn = *(const float4*)(w_all + (long)pn * MEMN + q * 8 + 4);
    const u16 en = eras[(long)pn * DVN + c];
    const u16 an = addb[(long)pn * DVN + c];

    const float wr[8] = {wA.x, wA.y, wA.z, wA.w, wB.x, wB.y, wB.z, wB.w};
    float pr = 0.f;
    #pragma unroll
    for (int i = 0; i < 8; ++i) pr = fmaf(wr[i], Mv[i], pr);
    pr += __shfl_xor(pr, 1, 64);
    pr += __shfl_xor(pr, 2, 64);
    if (q == 0) sin_buf[(long)p * DSN + c] = f2bf(pr);
    #pragma unroll
    for (int i = 0; i < 8; ++i) {
      const float t1 = wr[i] * ec;
      const float u  = fmaf(wr[i], ac, Mv[i]);
      Mv[i] = fmaf(-Mv[i], t1, u);
    }
    wA = wAn; wB = wBn; ec = bf2f(en); ac = bf2f(an);
  }
}

// ============================================================
// kOut: combine. grid (BSN/256), block 256. f32 output.
// ============================================================
__global__ __launch_bounds__(256) void kOut(
    const float* __restrict__ part, const float* __restrict__ diff,
    const float* __restrict__ bab2, float* __restrict__ out)
{
  const int p = blockIdx.x * 256 + threadIdx.x;
  const float ab = part[p] + part[BSN + p] + bab2[0];
  const float d  = diff[p];
  const float z  = 3.0f * ab - d;
  out[p]           = sigmoid_fast(z);
  out[BSN + p]     = ab;
  out[2 * BSN + p] = d;
  out[3 * BSN + p] = z;
}

// ============================================================
// launch
// ============================================================
extern "C" void kernel_launch(void* const* d_in, const int* in_sizes, int n_in,
                              void* d_out, int out_size, void* d_ws, size_t ws_size,
                              hipStream_t stream)
{
  const int*   q_data   = (const int*)d_in[0];
  const int*   qa_data  = (const int*)d_in[1];
  const float* q_table  = (const float*)d_in[2];
  const float* qa_table = (const float*)d_in[3];
  const float* key_mem  = (const float*)d_in[4];
  const float* init_mem = (const float*)d_in[5];
  const float* W_erase  = (const float*)d_in[6];
  const float* b_erase  = (const float*)d_in[7];
  const float* W_add    = (const float*)d_in[8];
  const float* b_add    = (const float*)d_in[9];
  const float* W_sum    = (const float*)d_in[10];
  const float* b_sum    = (const float*)d_in[11];
  const float* W_ab1    = (const float*)d_in[12];
  const float* b_ab1    = (const float*)d_in[13];
  const float* W_ab2    = (const float*)d_in[14];
  const float* b_ab2    = (const float*)d_in[15];
  const float* W_df1    = (const float*)d_in[16];
  const float* b_df1    = (const float*)d_in[17];
  const float* W_df2    = (const float*)d_in[18];
  const float* b_df2    = (const float*)d_in[19];

  // workspace layout (bytes); total 152,936,448
  char* ws = (char*)d_ws;
  float* w_all = (float*)(ws + 0);           // [BS][32] f32   16,777,216
  u16*   eras  = (u16*)(ws + 16777216);      // [BS][128] bf16 33,554,432
  u16*   addb  = (u16*)(ws + 50331648);      // [BS][128] bf16 33,554,432
  u16*   sinb  = (u16*)(ws + 83886080);      // [BS][256] bf16 67,108,864
  float* diffb = (float*)(ws + 150994944);   // [BS] f32          524,288
  float* part  = (float*)(ws + 151519232);   // [2][BS] f32     1,048,576
  u16*   WerT  = (u16*)(ws + 152567808);     // 32,768
  u16*   WaddT = (u16*)(ws + 152600576);     // 32,768
  u16*   WsumT = (u16*)(ws + 152633344);     // 131,072
  u16*   Wab1T = (u16*)(ws + 152764416);     // 131,072
  u16*   BqT   = (u16*)(ws + 152895488);     // 160x128 bf16 = 40,960
  u16*   summ  = eras;                       // summary reuses eras+addb

  kPrep<<<dim3(720), 256, 0, stream>>>(W_sum, W_ab1, W_erase, W_add, key_mem, W_df1,
                                       WsumT, Wab1T, WerT, WaddT, BqT);
  kErAdd<<<dim3(BSN / 128, 2), 256, 0, stream>>>(qa_data, qa_table, WerT, WaddT,
                                                 b_erase, b_add, eras, addb);
  kQe<<<dim3(BSN / 128), 256, 0, stream>>>(q_data, q_table, BqT, b_df1, W_df2, b_df2,
                                           w_all, diffb, sinb);
  kScan<<<dim3(B_N), 512, 0, stream>>>(w_all, eras, addb, init_mem, sinb);
  kSum<<<dim3(BSN / 128, 2), 256, 0, stream>>>(sinb, WsumT, b_sum, summ);
  kAb<<<dim3(BSN / 128, 2), 256, 0, stream>>>(summ, Wab1T, b_ab1, W_ab2, part);
  kOut<<<dim3(BSN / 256), 256, 0, stream>>>(part, diffb, b_ab2, (float*)d_out);
}

// Round 6
// 406.859 us; speedup vs baseline: 4.4340x; 1.2330x over previous
//
#include <hip/hip_runtime.h>
#include <hip/hip_bf16.h>

typedef unsigned short u16;
typedef unsigned int   u32;

#define B_N   256
#define S_N   512
#define BSN   (B_N * S_N)      // 131072 positions
#define MEMN  32
#define DKN   128
#define DVN   128
#define DSN   256

typedef __attribute__((ext_vector_type(8))) short bf16x8;
typedef __attribute__((ext_vector_type(4))) float f32x4;

// ---------- helpers ----------
__device__ __forceinline__ float bf2f(u16 u) {
  union { u32 i; float f; } v; v.i = ((u32)u) << 16; return v.f;
}
__device__ __forceinline__ u16 f2bf(float f) {
  union { float f; u32 i; } v; v.f = f;
  u32 x = v.i;
  x += 0x7fffu + ((x >> 16) & 1u);   // RNE
  return (u16)(x >> 16);
}
__device__ __forceinline__ u32 pack2(float a, float b) {
  return (u32)f2bf(a) | ((u32)f2bf(b) << 16);
}
__device__ __forceinline__ float sigmoid_fast(float x) { return 1.f / (1.f + __expf(-x)); }
__device__ __forceinline__ float tanh_fast(float x)    { return 1.f - 2.f / (__expf(2.f * x) + 1.f); }

// ============================================================
// kPrep: transpose + bf16-convert weights; build concatenated BqT:
// BqT[n][k], n<32: key_mem[n][k]; n>=32: W_df1[k][n-32].   184320 elems.
// ============================================================
__global__ __launch_bounds__(256) void kPrep(
    const float* __restrict__ W_sum, const float* __restrict__ W_ab1,
    const float* __restrict__ W_er,  const float* __restrict__ W_ad,
    const float* __restrict__ key_mem, const float* __restrict__ W_df1,
    u16* __restrict__ WsumT, u16* __restrict__ Wab1T,
    u16* __restrict__ WerT,  u16* __restrict__ WaddT,
    u16* __restrict__ BqT)
{
  int e = blockIdx.x * 256 + threadIdx.x;
  if (e < 65536) {
    const int n = e >> 8, k = e & 255;
    WsumT[e] = f2bf(W_sum[k * 256 + n]);
  } else if (e < 131072) {
    e -= 65536;
    const int n = e >> 8, k = e & 255;
    Wab1T[e] = f2bf(W_ab1[k * 256 + n]);
  } else if (e < 147456) {
    e -= 131072;
    const int n = e >> 7, k = e & 127;
    WerT[e] = f2bf(W_er[k * 128 + n]);
  } else if (e < 163840) {
    e -= 147456;
    const int n = e >> 7, k = e & 127;
    WaddT[e] = f2bf(W_ad[k * 128 + n]);
  } else if (e < 184320) {
    e -= 163840;
    const int n = e >> 7, k = e & 127;
    BqT[e] = f2bf(n < 32 ? key_mem[n * 128 + k] : W_df1[k * 128 + (n - 32)]);
  }
}

// ============================================================
// kErAdd: MFMA GEMM. out = act(qae @ W + b), W pre-transposed bf16.
// grid (BSN/128, 2), block 256 (4 waves, 64x64 tiles). y: 0=erase, 1=add.
// ============================================================
__global__ __launch_bounds__(256) void kErAdd(
    const int* __restrict__ qa_data, const float* __restrict__ qa_table,
    const u16* __restrict__ WerT, const u16* __restrict__ WaddT,
    const float* __restrict__ b_er, const float* __restrict__ b_ad,
    u16* __restrict__ eras, u16* __restrict__ addb)
{
  __shared__ __align__(16) u16 As[4 * 128 * 32];   // [chunk][m][k'] 32 KB
  __shared__ __align__(16) u16 Bs[2 * 128 * 32];   // dbuf [n][k'] 16 KB
  const int tid = threadIdx.x;
  const int p0  = blockIdx.x * 128;
  const int sel = blockIdx.y;
  const u16*   Wt = sel ? WaddT : WerT;
  const float* bb = sel ? b_ad  : b_er;
  u16*       outp = sel ? addb  : eras;

  // ---- stage A: gather 128 rows of qa_table (f32 -> bf16), chunked layout
  {
    const int r = tid >> 1, h = tid & 1;
    const long base = (long)qa_data[p0 + r] * DVN + h * 64;
    #pragma unroll
    for (int g = 0; g < 8; ++g) {
      const int k0 = h * 64 + g * 8;
      const float4 fa = *(const float4*)(qa_table + base + g * 8);
      const float4 fb = *(const float4*)(qa_table + base + g * 8 + 4);
      uint4 pk;
      pk.x = pack2(fa.x, fa.y); pk.y = pack2(fa.z, fa.w);
      pk.z = pack2(fb.x, fb.y); pk.w = pack2(fb.z, fb.w);
      *(uint4*)(As + (k0 >> 5) * 4096 + r * 32 + (k0 & 31)) = pk;
    }
  }
  // ---- stage B chunk 0
  {
    #pragma unroll
    for (int u = 0; u < 2; ++u) {
      const int f = tid + 256 * u;           // 0..511
      const int n = f >> 2, j = f & 3;
      *(uint4*)(Bs + n * 32 + j * 8) = *(const uint4*)(Wt + n * 128 + j * 8);
    }
  }
  __syncthreads();

  const int lane = tid & 63, wave = tid >> 6;
  const int wr = (wave >> 1) * 64, wc = (wave & 1) * 64;
  const int c15 = lane & 15, q = lane >> 4;

  f32x4 acc[4][4];
  #pragma unroll
  for (int b = 0; b < 4; ++b) {
    const float bv = bb[wc + 16 * b + c15];
    #pragma unroll
    for (int a = 0; a < 4; ++a) acc[a][b] = (f32x4){bv, bv, bv, bv};
  }

  for (int c = 0; c < 4; ++c) {
    const int cur = c & 1;
    uint4 st[2];
    const bool more = (c + 1 < 4);
    if (more) {
      #pragma unroll
      for (int u = 0; u < 2; ++u) {
        const int f = tid + 256 * u;
        const int n = f >> 2, j = f & 3;
        st[u] = *(const uint4*)(Wt + n * 128 + (c + 1) * 32 + j * 8);
      }
    }
    bf16x8 af[4], bf[4];
    #pragma unroll
    for (int a = 0; a < 4; ++a)
      af[a] = *(const bf16x8*)(As + c * 4096 + (wr + 16 * a + c15) * 32 + q * 8);
    #pragma unroll
    for (int b = 0; b < 4; ++b)
      bf[b] = *(const bf16x8*)(Bs + cur * 4096 + (wc + 16 * b + c15) * 32 + q * 8);
    #pragma unroll
    for (int a = 0; a < 4; ++a)
      #pragma unroll
      for (int b = 0; b < 4; ++b)
        acc[a][b] = __builtin_amdgcn_mfma_f32_16x16x32_bf16(af[a], bf[b], acc[a][b], 0, 0, 0);
    if (more) {
      #pragma unroll
      for (int u = 0; u < 2; ++u) {
        const int f = tid + 256 * u;
        const int n = f >> 2, j = f & 3;
        *(uint4*)(Bs + (cur ^ 1) * 4096 + n * 32 + j * 8) = st[u];
      }
    }
    __syncthreads();
  }

  // ---- epilogue: activation + u16 stores
  const int colb = wc + c15;
  #pragma unroll
  for (int a = 0; a < 4; ++a) {
    #pragma unroll
    for (int r = 0; r < 4; ++r) {
      const int row = p0 + wr + 16 * a + 4 * q + r;
      u16* yp = outp + (long)row * DVN + colb;
      #pragma unroll
      for (int b = 0; b < 4; ++b) {
        const float v = sel ? tanh_fast(acc[a][b][r]) : sigmoid_fast(acc[a][b][r]);
        yp[16 * b] = f2bf(v);
      }
    }
  }
}

// ============================================================
// kSum: MFMA GEMM. summary = tanh(sin @ W_sum + b). K=256 (8 chunks).
// grid (BSN/128, 2: col half). LDS: A 64KB + B 16KB = 80KB.
// ============================================================
__global__ __launch_bounds__(256) void kSum(
    const u16* __restrict__ X, const u16* __restrict__ WsumT,
    const float* __restrict__ bias, u16* __restrict__ Y)
{
  __shared__ __align__(16) u16 As[8 * 128 * 32];   // 64 KB
  __shared__ __align__(16) u16 Bs[2 * 128 * 32];   // 16 KB
  const int tid = threadIdx.x;
  const int p0  = blockIdx.x * 128;
  const int j0  = blockIdx.y * 128;

  { // stage A (bf16 copy, chunked) — FULL K coverage: 4096 uint4
    #pragma unroll
    for (int u = 0; u < 16; ++u) {
      const int f = tid + 256 * u;           // 0..4095
      const int r = f >> 5, j = f & 31;      // r: row 0..127, j: k-octet 0..31
      const uint4 raw = *(const uint4*)(X + (long)(p0 + r) * DSN + j * 8);
      *(uint4*)(As + (j >> 2) * 4096 + r * 32 + (j & 3) * 8) = raw;
    }
  }
  { // stage B chunk 0
    #pragma unroll
    for (int u = 0; u < 2; ++u) {
      const int f = tid + 256 * u;
      const int n = f >> 2, j = f & 3;
      *(uint4*)(Bs + n * 32 + j * 8) = *(const uint4*)(WsumT + (j0 + n) * 256 + j * 8);
    }
  }
  __syncthreads();

  const int lane = tid & 63, wave = tid >> 6;
  const int wr = (wave >> 1) * 64, wc = (wave & 1) * 64;
  const int c15 = lane & 15, q = lane >> 4;

  f32x4 acc[4][4];
  #pragma unroll
  for (int b = 0; b < 4; ++b) {
    const float bv = bias[j0 + wc + 16 * b + c15];
    #pragma unroll
    for (int a = 0; a < 4; ++a) acc[a][b] = (f32x4){bv, bv, bv, bv};
  }

  for (int c = 0; c < 8; ++c) {
    const int cur = c & 1;
    uint4 st[2];
    const bool more = (c + 1 < 8);
    if (more) {
      #pragma unroll
      for (int u = 0; u < 2; ++u) {
        const int f = tid + 256 * u;
        const int n = f >> 2, j = f & 3;
        st[u] = *(const uint4*)(WsumT + (j0 + n) * 256 + (c + 1) * 32 + j * 8);
      }
    }
    bf16x8 af[4], bf[4];
    #pragma unroll
    for (int a = 0; a < 4; ++a)
      af[a] = *(const bf16x8*)(As + c * 4096 + (wr + 16 * a + c15) * 32 + q * 8);
    #pragma unroll
    for (int b = 0; b < 4; ++b)
      bf[b] = *(const bf16x8*)(Bs + cur * 4096 + (wc + 16 * b + c15) * 32 + q * 8);
    #pragma unroll
    for (int a = 0; a < 4; ++a)
      #pragma unroll
      for (int b = 0; b < 4; ++b)
        acc[a][b] = __builtin_amdgcn_mfma_f32_16x16x32_bf16(af[a], bf[b], acc[a][b], 0, 0, 0);
    if (more) {
      #pragma unroll
      for (int u = 0; u < 2; ++u) {
        const int f = tid + 256 * u;
        const int n = f >> 2, j = f & 3;
        *(uint4*)(Bs + (cur ^ 1) * 4096 + n * 32 + j * 8) = st[u];
      }
    }
    __syncthreads();
  }

  const int colb = j0 + wc + c15;
  #pragma unroll
  for (int a = 0; a < 4; ++a) {
    #pragma unroll
    for (int r = 0; r < 4; ++r) {
      const int row = p0 + wr + 16 * a + 4 * q + r;
      u16* yp = Y + (long)row * DSN + colb;
      #pragma unroll
      for (int b = 0; b < 4; ++b)
        yp[16 * b] = f2bf(tanh_fast(acc[a][b][r]));
    }
  }
}

// ============================================================
// kAb: MFMA GEMM + fused W_ab2 dot.
// ============================================================
__global__ __launch_bounds__(256) void kAb(
    const u16* __restrict__ X, const u16* __restrict__ Wab1T,
    const float* __restrict__ bias, const float* __restrict__ Wab2,
    float* __restrict__ part)
{
  __shared__ __align__(16) u16 As[8 * 128 * 32];
  __shared__ __align__(16) u16 Bs[2 * 128 * 32];
  const int tid = threadIdx.x;
  const int p0  = blockIdx.x * 128;
  const int j0  = blockIdx.y * 128;

  { // stage A — FULL K coverage: 4096 uint4
    #pragma unroll
    for (int u = 0; u < 16; ++u) {
      const int f = tid + 256 * u;
      const int r = f >> 5, j = f & 31;
      const uint4 raw = *(const uint4*)(X + (long)(p0 + r) * DSN + j * 8);
      *(uint4*)(As + (j >> 2) * 4096 + r * 32 + (j & 3) * 8) = raw;
    }
  }
  {
    #pragma unroll
    for (int u = 0; u < 2; ++u) {
      const int f = tid + 256 * u;
      const int n = f >> 2, j = f & 3;
      *(uint4*)(Bs + n * 32 + j * 8) = *(const uint4*)(Wab1T + (j0 + n) * 256 + j * 8);
    }
  }
  __syncthreads();

  const int lane = tid & 63, wave = tid >> 6;
  const int wr = (wave >> 1) * 64, wc = (wave & 1) * 64;
  const int c15 = lane & 15, q = lane >> 4;

  f32x4 acc[4][4];
  float w2v[4];
  #pragma unroll
  for (int b = 0; b < 4; ++b) {
    const int col = j0 + wc + 16 * b + c15;
    const float bv = bias[col];
    w2v[b] = Wab2[col];
    #pragma unroll
    for (int a = 0; a < 4; ++a) acc[a][b] = (f32x4){bv, bv, bv, bv};
  }

  for (int c = 0; c < 8; ++c) {
    const int cur = c & 1;
    uint4 st[2];
    const bool more = (c + 1 < 8);
    if (more) {
      #pragma unroll
      for (int u = 0; u < 2; ++u) {
        const int f = tid + 256 * u;
        const int n = f >> 2, j = f & 3;
        st[u] = *(const uint4*)(Wab1T + (j0 + n) * 256 + (c + 1) * 32 + j * 8);
      }
    }
    bf16x8 af[4], bf[4];
    #pragma unroll
    for (int a = 0; a < 4; ++a)
      af[a] = *(const bf16x8*)(As + c * 4096 + (wr + 16 * a + c15) * 32 + q * 8);
    #pragma unroll
    for (int b = 0; b < 4; ++b)
      bf[b] = *(const bf16x8*)(Bs + cur * 4096 + (wc + 16 * b + c15) * 32 + q * 8);
    #pragma unroll
    for (int a = 0; a < 4; ++a)
      #pragma unroll
      for (int b = 0; b < 4; ++b)
        acc[a][b] = __builtin_amdgcn_mfma_f32_16x16x32_bf16(af[a], bf[b], acc[a][b], 0, 0, 0);
    if (more) {
      #pragma unroll
      for (int u = 0; u < 2; ++u) {
        const int f = tid + 256 * u;
        const int n = f >> 2, j = f & 3;
        *(uint4*)(Bs + (cur ^ 1) * 4096 + n * 32 + j * 8) = st[u];
      }
    }
    __syncthreads();   // final barrier also fences Bs reuse below
  }

  // ---- epilogue: tanh, dot with W_ab2, reduce 16 col-lanes, pair waves
  float sv[4][4];
  #pragma unroll
  for (int a = 0; a < 4; ++a) {
    #pragma unroll
    for (int r = 0; r < 4; ++r) {
      float s = 0.f;
      #pragma unroll
      for (int b = 0; b < 4; ++b)
        s = fmaf(tanh_fast(acc[a][b][r]), w2v[b], s);
      s += __shfl_xor(s, 1, 64);
      s += __shfl_xor(s, 2, 64);
      s += __shfl_xor(s, 4, 64);
      s += __shfl_xor(s, 8, 64);
      sv[a][r] = s;
    }
  }
  float* red = (float*)Bs;   // 128 f32, reuse (fenced by loop's last barrier)
  if ((wave & 1) && c15 == 0) {
    #pragma unroll
    for (int a = 0; a < 4; ++a)
      #pragma unroll
      for (int r = 0; r < 4; ++r)
        red[wr + 16 * a + 4 * q + r] = sv[a][r];
  }
  __syncthreads();
  if (!(wave & 1) && c15 == 0) {
    #pragma unroll
    for (int a = 0; a < 4; ++a)
      #pragma unroll
      for (int r = 0; r < 4; ++r) {
        const int rr = wr + 16 * a + 4 * q + r;
        part[(long)blockIdx.y * BSN + p0 + rr] = sv[a][r] + red[rr];
      }
  }
}

// ============================================================
// kQe (MFMA): one GEMM qe[128x128] @ BqT^T[128x160] per block.
// cols 0..31 = attention scores -> softmax -> w_all
// cols 32..159 = df hidden -> tanh -> dot W_df2 -> diff
// qe -> sinb copy fused into A staging.
// ============================================================
__global__ __launch_bounds__(256) void kQe(
    const int* __restrict__ q_data, const float* __restrict__ q_table,
    const u16* __restrict__ BqT,
    const float* __restrict__ bdf1, const float* __restrict__ Wdf2,
    const float* __restrict__ bdf2,
    float* __restrict__ w_all, float* __restrict__ diff,
    u16* __restrict__ sin_buf)
{
  __shared__ __align__(16) u16 As[4 * 128 * 32];   // 32 KB [chunk][row][k']
  __shared__ __align__(16) u16 Bs[4 * 160 * 32];   // 40 KB [chunk][n][k']
  const int tid = threadIdx.x;
  const int p0  = blockIdx.x * 128;

  // ---- stage A: gather qe rows (f32->bf16), fused sinb store
  {
    const int r = tid >> 1, h = tid & 1;
    const long base = (long)q_data[p0 + r] * DKN + h * 64;
    #pragma unroll
    for (int g = 0; g < 8; ++g) {
      const int k0 = h * 64 + g * 8;
      const float4 fa = *(const float4*)(q_table + base + g * 8);
      const float4 fb = *(const float4*)(q_table + base + g * 8 + 4);
      uint4 pk;
      pk.x = pack2(fa.x, fa.y); pk.y = pack2(fa.z, fa.w);
      pk.z = pack2(fb.x, fb.y); pk.w = pack2(fb.z, fb.w);
      *(uint4*)(As + (k0 >> 5) * 4096 + r * 32 + (k0 & 31)) = pk;
      *(uint4*)(sin_buf + (long)(p0 + r) * DSN + DKN + k0) = pk;
    }
  }
  // ---- stage B: 160 rows x 128 k = 2560 uint4 (10/thread)
  {
    #pragma unroll
    for (int u = 0; u < 10; ++u) {
      const int f = tid + 256 * u;           // 0..2559
      const int n = f >> 4, jj = f & 15;
      *(uint4*)(Bs + (jj >> 2) * 5120 + n * 32 + (jj & 3) * 8) =
          *(const uint4*)(BqT + n * 128 + jj * 8);
    }
  }
  __syncthreads();

  const int lane = tid & 63, wave = tid >> 6;
  const int wr = (wave >> 1) * 64, wc = (wave & 1) * 80;
  const int c15 = lane & 15, q = lane >> 4;

  f32x4 acc[4][5];
  float w2v[5];
  #pragma unroll
  for (int b = 0; b < 5; ++b) {
    const int col = wc + 16 * b + c15;
    const float bv = (col < 32) ? 0.f : bdf1[col - 32];
    w2v[b] = (col < 32) ? 0.f : Wdf2[col - 32];
    #pragma unroll
    for (int a = 0; a < 4; ++a) acc[a][b] = (f32x4){bv, bv, bv, bv};
  }

  #pragma unroll
  for (int c = 0; c < 4; ++c) {
    bf16x8 af[4], bf[5];
    #pragma unroll
    for (int a = 0; a < 4; ++a)
      af[a] = *(const bf16x8*)(As + c * 4096 + (wr + 16 * a + c15) * 32 + q * 8);
    #pragma unroll
    for (int b = 0; b < 5; ++b)
      bf[b] = *(const bf16x8*)(Bs + c * 5120 + (wc + 16 * b + c15) * 32 + q * 8);
    #pragma unroll
    for (int a = 0; a < 4; ++a)
      #pragma unroll
      for (int b = 0; b < 5; ++b)
        acc[a][b] = __builtin_amdgcn_mfma_f32_16x16x32_bf16(af[a], bf[b], acc[a][b], 0, 0, 0);
  }

  // ---- softmax over cols 0..31 (waves with wc==0 only: b=0,1)
  if (wc == 0) {
    #pragma unroll
    for (int a = 0; a < 4; ++a) {
      #pragma unroll
      for (int r = 0; r < 4; ++r) {
        float s0 = acc[a][0][r], s1 = acc[a][1][r];
        float mx = fmaxf(s0, s1);
        mx = fmaxf(mx, __shfl_xor(mx, 1, 64));
        mx = fmaxf(mx, __shfl_xor(mx, 2, 64));
        mx = fmaxf(mx, __shfl_xor(mx, 4, 64));
        mx = fmaxf(mx, __shfl_xor(mx, 8, 64));
        const float e0 = __expf(s0 - mx), e1 = __expf(s1 - mx);
        float sm = e0 + e1;
        sm += __shfl_xor(sm, 1, 64);
        sm += __shfl_xor(sm, 2, 64);
        sm += __shfl_xor(sm, 4, 64);
        sm += __shfl_xor(sm, 8, 64);
        const float inv = 1.f / sm;
        const int row = p0 + wr + 16 * a + 4 * q + r;
        w_all[(long)row * MEMN + c15]      = e0 * inv;
        w_all[(long)row * MEMN + 16 + c15] = e1 * inv;
      }
    }
  }

  // ---- diff partials: tanh + W_df2 dot (w2v==0 masks attention cols)
  float sv[4][4];
  #pragma unroll
  for (int a = 0; a < 4; ++a) {
    #pragma unroll
    for (int r = 0; r < 4; ++r) {
      float s = 0.f;
      #pragma unroll
      for (int b = 0; b < 5; ++b)
        s = fmaf(tanh_fast(acc[a][b][r]), w2v[b], s);
      s += __shfl_xor(s, 1, 64);
      s += __shfl_xor(s, 2, 64);
      s += __shfl_xor(s, 4, 64);
      s += __shfl_xor(s, 8, 64);
      sv[a][r] = s;
    }
  }
  __syncthreads();               // all MFMA LDS reads done; reuse As
  float* red = (float*)As;       // 128 f32
  if ((wave & 1) && c15 == 0) {  // wc==80 waves
    #pragma unroll
    for (int a = 0; a < 4; ++a)
      #pragma unroll
      for (int r = 0; r < 4; ++r)
        red[wr + 16 * a + 4 * q + r] = sv[a][r];
  }
  __syncthreads();
  if (!(wave & 1) && c15 == 0) {
    const float bd = bdf2[0];
    #pragma unroll
    for (int a = 0; a < 4; ++a)
      #pragma unroll
      for (int r = 0; r < 4; ++r) {
        const int rr = wr + 16 * a + 4 * q + r;
        diff[p0 + rr] = sv[a][r] + red[rr] + bd;
      }
  }
}

// ============================================================
// kScan: sequential DKVMN recurrence with DEEP register prefetch.
// grid (B_N), block 512. thread: col c = tid>>2, rows (tid&3)*8..+7.
// Two 8-step register groups; refill group G+2's slot after computing G.
// Prefetch lead ~1 full group of compute (>= HBM latency). Junk reads
// past s=511 stay inside d_ws (next buffer region) and are never used.
// ============================================================
#define KS_PREF(WA, WB, EE, AA, SB)                                        \
  {                                                                        \
    _Pragma("unroll")                                                      \
    for (int j = 0; j < 8; ++j) {                                          \
      WA[j] = *(const float4*)(wp + (long)((SB) + j) * MEMN);              \
      WB[j] = *(const float4*)(wp + (long)((SB) + j) * MEMN + 4);          \
      EE[j] = ep[(long)((SB) + j) * DVN];                                  \
      AA[j] = ap[(long)((SB) + j) * DVN];                                  \
    }                                                                      \
  }

#define KS_COMP(WA, WB, EE, AA, SB)                                        \
  {                                                                        \
    _Pragma("unroll")                                                      \
    for (int j = 0; j < 8; ++j) {                                          \
      const float wv[8] = {WA[j].x, WA[j].y, WA[j].z, WA[j].w,             \
                           WB[j].x, WB[j].y, WB[j].z, WB[j].w};            \
      float pr = 0.f;                                                      \
      _Pragma("unroll")                                                    \
      for (int i = 0; i < 8; ++i) pr = fmaf(wv[i], Mv[i], pr);             \
      pr += __shfl_xor(pr, 1, 64);                                         \
      pr += __shfl_xor(pr, 2, 64);                                         \
      if (q == 0) sp[(long)((SB) + j) * DSN] = f2bf(pr);                   \
      const float ec = bf2f((u16)EE[j]);                                   \
      const float ac = bf2f((u16)AA[j]);                                   \
      _Pragma("unroll")                                                    \
      for (int i = 0; i < 8; ++i) {                                        \
        const float t1 = wv[i] * ec;                                       \
        const float uu = fmaf(wv[i], ac, Mv[i]);                           \
        Mv[i] = fmaf(-Mv[i], t1, uu);                                      \
      }                                                                    \
    }                                                                      \
  }

__global__ __launch_bounds__(512, 2) void kScan(
    const float* __restrict__ w_all, const u16* __restrict__ eras,
    const u16* __restrict__ addb, const float* __restrict__ init_mem,
    u16* __restrict__ sin_buf)
{
  const int tid = threadIdx.x;
  const int c = tid >> 2;
  const int q = tid & 3;
  float Mv[8];
  #pragma unroll
  for (int i = 0; i < 8; ++i) Mv[i] = init_mem[(q * 8 + i) * DVN + c];

  const long pbase = (long)blockIdx.x * S_N;
  const float* wp = w_all + pbase * MEMN + q * 8;
  const u16*   ep = eras + pbase * DVN + c;
  const u16*   ap = addb + pbase * DVN + c;
  u16*         sp = sin_buf + pbase * DSN + c;

  float4 wA0[8], wB0[8], wA1[8], wB1[8];
  u32 e0[8], a0[8], e1[8], a1[8];

  KS_PREF(wA0, wB0, e0, a0, 0)
  KS_PREF(wA1, wB1, e1, a1, 8)

  for (int s0 = 0; s0 < S_N; s0 += 16) {
    KS_COMP(wA0, wB0, e0, a0, s0)
    KS_PREF(wA0, wB0, e0, a0, s0 + 16)        // junk past 511, unused
    KS_COMP(wA1, wB1, e1, a1, s0 + 8)
    KS_PREF(wA1, wB1, e1, a1, s0 + 24)
  }
}

// ============================================================
// kOut: combine. grid (BSN/256), block 256. f32 output.
// ============================================================
__global__ __launch_bounds__(256) void kOut(
    const float* __restrict__ part, const float* __restrict__ diff,
    const float* __restrict__ bab2, float* __restrict__ out)
{
  const int p = blockIdx.x * 256 + threadIdx.x;
  const float ab = part[p] + part[BSN + p] + bab2[0];
  const float d  = diff[p];
  const float z  = 3.0f * ab - d;
  out[p]           = sigmoid_fast(z);
  out[BSN + p]     = ab;
  out[2 * BSN + p] = d;
  out[3 * BSN + p] = z;
}

// ============================================================
// launch
// ============================================================
extern "C" void kernel_launch(void* const* d_in, const int* in_sizes, int n_in,
                              void* d_out, int out_size, void* d_ws, size_t ws_size,
                              hipStream_t stream)
{
  const int*   q_data   = (const int*)d_in[0];
  const int*   qa_data  = (const int*)d_in[1];
  const float* q_table  = (const float*)d_in[2];
  const float* qa_table = (const float*)d_in[3];
  const float* key_mem  = (const float*)d_in[4];
  const float* init_mem = (const float*)d_in[5];
  const float* W_erase  = (const float*)d_in[6];
  const float* b_erase  = (const float*)d_in[7];
  const float* W_add    = (const float*)d_in[8];
  const float* b_add    = (const float*)d_in[9];
  const float* W_sum    = (const float*)d_in[10];
  const float* b_sum    = (const float*)d_in[11];
  const float* W_ab1    = (const float*)d_in[12];
  const float* b_ab1    = (const float*)d_in[13];
  const float* W_ab2    = (const float*)d_in[14];
  const float* b_ab2    = (const float*)d_in[15];
  const float* W_df1    = (const float*)d_in[16];
  const float* b_df1    = (const float*)d_in[17];
  const float* W_df2    = (const float*)d_in[18];
  const float* b_df2    = (const float*)d_in[19];

  // workspace layout (bytes); total 152,936,448
  char* ws = (char*)d_ws;
  float* w_all = (float*)(ws + 0);           // [BS][32] f32   16,777,216
  u16*   eras  = (u16*)(ws + 16777216);      // [BS][128] bf16 33,554,432
  u16*   addb  = (u16*)(ws + 50331648);      // [BS][128] bf16 33,554,432
  u16*   sinb  = (u16*)(ws + 83886080);      // [BS][256] bf16 67,108,864
  float* diffb = (float*)(ws + 150994944);   // [BS] f32          524,288
  float* part  = (float*)(ws + 151519232);   // [2][BS] f32     1,048,576
  u16*   WerT  = (u16*)(ws + 152567808);     // 32,768
  u16*   WaddT = (u16*)(ws + 152600576);     // 32,768
  u16*   WsumT = (u16*)(ws + 152633344);     // 131,072
  u16*   Wab1T = (u16*)(ws + 152764416);     // 131,072
  u16*   BqT   = (u16*)(ws + 152895488);     // 160x128 bf16 = 40,960
  u16*   summ  = eras;                       // summary reuses eras+addb

  kPrep<<<dim3(720), 256, 0, stream>>>(W_sum, W_ab1, W_erase, W_add, key_mem, W_df1,
                                       WsumT, Wab1T, WerT, WaddT, BqT);
  kErAdd<<<dim3(BSN / 128, 2), 256, 0, stream>>>(qa_data, qa_table, WerT, WaddT,
                                                 b_erase, b_add, eras, addb);
  kQe<<<dim3(BSN / 128), 256, 0, stream>>>(q_data, q_table, BqT, b_df1, W_df2, b_df2,
                                           w_all, diffb, sinb);
  kScan<<<dim3(B_N), 512, 0, stream>>>(w_all, eras, addb, init_mem, sinb);
  kSum<<<dim3(BSN / 128, 2), 256, 0, stream>>>(sinb, WsumT, b_sum, summ);
  kAb<<<dim3(BSN / 128, 2), 256, 0, stream>>>(summ, Wab1T, b_ab1, W_ab2, part);
  kOut<<<dim3(BSN / 256), 256, 0, stream>>>(part, diffb, b_ab2, (float*)d_out);
}